// Round 18
// baseline (58.604 us; speedup 1.0000x reference)
//
#include <hip/hip_runtime.h>
#include <stdint.h>

#define V 50257
#define B_ 64
#define S_ 8
#define ROWS (B_ * S_)
#define L_ 2048
#define NEG_INF -1000000000.0f
#define PEN_NEG (-1200000000.0f)   // fp32(-1e9 * 1.2f), verified exact match
#define MASK_WORDS_PER_B 1571      // ceil(50257/32)
#define TOTAL (ROWS * V)           // 25,731,584
#define NVEC (TOTAL / 4)           // 6,432,896 (exact)
#define TOP_CAP 64                 // top-k=50 plus headroom for exact ties at kth
#define TRAW 2.8f                  // raw cutoff; E[cnt]=128/row
#define F4L 7                      // float4s per lane
#define WCHUNK_F4 (64 * F4L)       // 448 f4 per wave chunk
#define ELEMS_PER_WAVE (WCHUNK_F4 * 4)   // 1792 (spans <= 2 rows)
#define NWAVES ((NVEC + WCHUNK_F4 - 1) / WCHUNK_F4)   // 14360
#define GW_BLOCKS ((NWAVES + 3) / 4)                  // 3590
#define WCAP 32                    // per-wave region (mean 9.1, sd 3)
#define CAPROW 512                 // per-row candidate cap in select
#define BG_F4 2048                 // f4 per bg block
#define BG_BLOCKS ((NVEC + BG_F4 - 1) / BG_F4)       // 3142
#define BG_PRESW (BG_F4 * 4 / 32)                    // 256 words

// ---- workspace layout ----
#define WS_WCNT    0                                   // 14360 u32 -> pad 65536
#define WS_GCAND   65536                               // 14360*32*8 = 3,676,160
#define WS_NEED    (WS_GCAND + (size_t)NWAVES * WCAP * 8)   // ~3.74 MB
// fallback layout (disjoint use; only when ws too small for fast path)
#define WS_ROWPARAM 0                                   // 512 * 16 B
#define WS_MASK     8192                                // 402176 B

__device__ __forceinline__ unsigned fkey(float f) {
    unsigned u = __float_as_uint(f);
    return (u & 0x80000000u) ? ~u : (u | 0x80000000u);
}

__device__ __forceinline__ int blockReduceSum256(int v, int tid, int* s4) {
#pragma unroll
    for (int off = 32; off; off >>= 1) v += __shfl_down(v, off);
    __syncthreads();
    if ((tid & 63) == 0) s4[tid >> 6] = v;
    __syncthreads();
    return s4[0] + s4[1] + s4[2] + s4[3];
}

// ---------------- gather: per-wave one-shot (round-15 proven) ----------------

// Each wave owns f4 chunk [wid*448, +448). 7 asm loads, each followed by
// sched_barrier(0) so NOTHING (not even consumes) can interleave between the
// issues -> 7 truly outstanding loads/wave. One vmcnt(0)+sched_barrier, then
// consume into a depth-8 named-register shift queue. Wave-level prefix sum
// (shfl_up) assigns slots in the wave's PRIVATE gcand region; plain stores;
// lane 0 stores the count. Overflow (P~1e-12) flags select's exact fallback.
__global__ __launch_bounds__(256) void gather_kernel(const float4* __restrict__ in4,
                                                     uint2* __restrict__ gcand,
                                                     unsigned* __restrict__ wcnt) {
    const int wid = blockIdx.x * 4 + (threadIdx.x >> 6);
    if (wid >= NWAVES) return;
    const int lane = threadIdx.x & 63;
    const int b = wid * WCHUNK_F4 + lane;

    const float4* p0 = in4 + min(b,          NVEC - 1);
    const float4* p1 = in4 + min(b + 64,     NVEC - 1);
    const float4* p2 = in4 + min(b + 2 * 64, NVEC - 1);
    const float4* p3 = in4 + min(b + 3 * 64, NVEC - 1);
    const float4* p4 = in4 + min(b + 4 * 64, NVEC - 1);
    const float4* p5 = in4 + min(b + 5 * 64, NVEC - 1);
    const float4* p6 = in4 + min(b + 6 * 64, NVEC - 1);

    float4 va0, va1, va2, va3, va4, va5, va6;
#define LOADPIN(dst, src)                                                     \
    asm volatile("global_load_dwordx4 %0, %1, off" : "=v"(dst) : "v"(src));   \
    __builtin_amdgcn_sched_barrier(0);
    LOADPIN(va0, p0) LOADPIN(va1, p1) LOADPIN(va2, p2) LOADPIN(va3, p3)
    LOADPIN(va4, p4) LOADPIN(va5, p5) LOADPIN(va6, p6)
#undef LOADPIN
    asm volatile("s_waitcnt vmcnt(0)" ::: "memory");
    __builtin_amdgcn_sched_barrier(0);

    float q0v = 0.f, q1v = 0.f, q2v = 0.f, q3v = 0.f, q4v = 0.f, q5v = 0.f, q6v = 0.f, q7v = 0.f;
    int q0i = 0, q1i = 0, q2i = 0, q3i = 0, q4i = 0, q5i = 0, q6i = 0, q7i = 0;
    int nh = 0;

#define INS(val, ei)                                                          \
    if ((val) >= TRAW) {                                                      \
        q7v = q6v; q7i = q6i; q6v = q5v; q6i = q5i; q5v = q4v; q5i = q4i;     \
        q4v = q3v; q4i = q3i; q3v = q2v; q3i = q2i; q2v = q1v; q2i = q1i;     \
        q1v = q0v; q1i = q0i; q0v = (val); q0i = (ei); ++nh;                  \
    }
#define CONSUME(vv, kk)                                                       \
    {                                                                         \
        int i = b + (kk) * 64;                                                \
        if (i < NVEC) {                                                       \
            int e = i << 2;                                                   \
            INS((vv).x, e)                                                    \
            INS((vv).y, e + 1)                                                \
            INS((vv).z, e + 2)                                                \
            INS((vv).w, e + 3)                                                \
        }                                                                     \
    }
    CONSUME(va0, 0) CONSUME(va1, 1) CONSUME(va2, 2) CONSUME(va3, 3)
    CONSUME(va4, 4) CONSUME(va5, 5) CONSUME(va6, 6)
#undef CONSUME
#undef INS

    // wave prefix-sum of per-lane counts -> private slots; plain stores only
    int m = nh > 8 ? 8 : nh;
    int incl = m;
#pragma unroll
    for (int d = 1; d < 64; d <<= 1) {
        int t = __shfl_up(incl, d);
        if (lane >= d) incl += t;
    }
    int excl = incl - m;
    int total = __shfl(incl, 63);
    bool of = (total > WCAP) || __any(nh > 8);

    size_t rb = (size_t)wid * WCAP;
    if (m >= 1 && excl + 0 < WCAP) gcand[rb + excl + 0] = make_uint2((unsigned)q0i, __float_as_uint(q0v));
    if (m >= 2 && excl + 1 < WCAP) gcand[rb + excl + 1] = make_uint2((unsigned)q1i, __float_as_uint(q1v));
    if (m >= 3 && excl + 2 < WCAP) gcand[rb + excl + 2] = make_uint2((unsigned)q2i, __float_as_uint(q2v));
    if (m >= 4 && excl + 3 < WCAP) gcand[rb + excl + 3] = make_uint2((unsigned)q3i, __float_as_uint(q3v));
    if (m >= 5 && excl + 4 < WCAP) gcand[rb + excl + 4] = make_uint2((unsigned)q4i, __float_as_uint(q4v));
    if (m >= 6 && excl + 5 < WCAP) gcand[rb + excl + 5] = make_uint2((unsigned)q5i, __float_as_uint(q5v));
    if (m >= 7 && excl + 6 < WCAP) gcand[rb + excl + 6] = make_uint2((unsigned)q6i, __float_as_uint(q6v));
    if (m >= 8 && excl + 7 < WCAP) gcand[rb + excl + 7] = make_uint2((unsigned)q7i, __float_as_uint(q7v));
    if (lane == 0) wcnt[wid] = of ? 1000000u : (unsigned)total;
}

// ---------------- bg: pure background write stream (fill-shaped) ----------------

// Block owns f4 range [blk*BG_F4, end) — spans <= 2 rows, at most one of which
// is an s==7 (penalty) row. Pen blocks build an LDS range-presence bitmask
// from that batch's 2048 ids (round-8 validated logic); others are a pure
// constant fill. Kept tokens are overwritten later by select (kernel order).
__global__ __launch_bounds__(256) void bg_kernel(const int* __restrict__ ids,
                                                 float4* __restrict__ out4) {
    const int blk = blockIdx.x;
    const int tid = threadIdx.x;
    const int start = blk * BG_F4;
    const int end = min(start + BG_F4, NVEC);
    const unsigned baseE = (unsigned)start << 2;
    const unsigned endE = (unsigned)end << 2;

    __shared__ unsigned pres[BG_PRESW];

    unsigned r0 = baseE / (unsigned)V, r1 = (endE - 1u) / (unsigned)V;
    unsigned rl = ((r0 & 7u) == 7u) ? r0 : (((r1 & 7u) == 7u) ? r1 : 0xFFFFFFFFu);

    if (rl == 0xFFFFFFFFu) {
        const float4 bg = make_float4(NEG_INF, NEG_INF, NEG_INF, NEG_INF);
#pragma unroll
        for (int k = 0; k < 8; ++k) {
            int i = start + tid + k * 256;
            if (i < end) out4[i] = bg;
        }
        return;
    }
    for (int w = tid; w < BG_PRESW; w += 256) pres[w] = 0u;
    __syncthreads();
    const int* bp = ids + (rl >> 3) * L_;
    unsigned rowBase = rl * (unsigned)V;
#pragma unroll
    for (int k = 0; k < L_ / 256; ++k) {
        unsigned ge = rowBase + (unsigned)bp[k * 256 + tid];
        if (ge >= baseE && ge < endE) {
            unsigned off = ge - baseE;
            atomicOr(&pres[off >> 5], 1u << (off & 31));
        }
    }
    __syncthreads();
#pragma unroll
    for (int k = 0; k < 8; ++k) {
        int i = start + tid + k * 256;
        if (i < end) {
            unsigned off = ((unsigned)i << 2) - baseE;   // multiple of 4 -> one word
            unsigned pw = pres[off >> 5] >> (off & 31u);
            float4 bg;
            bg.x = (pw & 1u) ? PEN_NEG : NEG_INF;
            bg.y = (pw & 2u) ? PEN_NEG : NEG_INF;
            bg.z = (pw & 4u) ? PEN_NEG : NEG_INF;
            bg.w = (pw & 8u) ? PEN_NEG : NEG_INF;
            out4[i] = bg;
        }
    }
}

// ---------------- select: exact threshold + kept-value scatter only ----------------

// One 256-thread block per row. Exact reference semantics incl. fp32 ties
// (validated absmax=0): kth = 50th largest of x=v/0.8f; kept = ALL x >= kth;
// stable (x desc, idx asc) order; f64 softmax+cumsum decision. Background is
// already written by bg_kernel (previous launch); this kernel only scatters
// the ~50 kept values (penalized where present for s==7 rows).
__global__ __launch_bounds__(256) void select_kernel(const float* __restrict__ logits,
                                                     const int* __restrict__ ids,
                                                     const uint2* __restrict__ gcand,
                                                     const unsigned* __restrict__ wcnt,
                                                     float* __restrict__ out) {
    const int row = blockIdx.x;
    const int tid = threadIdx.x;
    __shared__ float cX[CAPROW];
    __shared__ int cI[CAPROW];
    __shared__ float sVal[TOP_CAP];
    __shared__ int sIdx[TOP_CAP];
    __shared__ double sExp[TOP_CAP];
    __shared__ unsigned presRow[MASK_WORDS_PER_B];
    __shared__ unsigned s_wc[40];
    __shared__ int s_c, s_M, s_bad, s_ti;
    __shared__ float s_t;
    __shared__ int s_red[4];

    const float* rp = logits + (size_t)row * V;
    const unsigned e0 = (unsigned)row * (unsigned)V;
    if (tid == 0) { s_c = 0; s_bad = 0; }
    __syncthreads();

    {   // flat parallel scan of the ~29 wave-regions overlapping this row
        const int r0 = (int)(e0 / (unsigned)ELEMS_PER_WAVE);
        const int r1 = (int)((e0 + V - 1) / (unsigned)ELEMS_PER_WAVE);
        const int nr = r1 - r0 + 1;                 // <= 30
        if (tid < nr) s_wc[tid] = wcnt[r0 + tid];
        __syncthreads();
        const int nslots = nr * WCAP;
        for (int j = tid; j < nslots; j += 256) {
            int r = j >> 5;                          // WCAP = 32
            int sl = j & 31;
            unsigned c = s_wc[r];
            if (c > (unsigned)WCAP) { s_bad = 1; c = WCAP; }   // benign race
            if (sl < (int)c) {
                uint2 u = gcand[(size_t)(r0 + r) * WCAP + sl];
                if (u.x / (unsigned)V == (unsigned)row) {
                    int p = atomicAdd(&s_c, 1);
                    if (p < CAPROW) {
                        cX[p] = __uint_as_float(u.y) / 0.8f;
                        cI[p] = (int)(u.x - e0);
                    }
                }
            }
        }
    }
    __syncthreads();
    int cnt = s_c;
    if (s_bad || cnt < 50 || cnt > CAPROW) {
        // Pathological-only exact fallback: bisect raw key space for the 50th
        // largest, re-gather with 2-ulp slack.
        unsigned lo = 0u, hi = 0xFFFFFFFFu;
        while (lo < hi) {
            unsigned mid = lo + ((hi - lo) >> 1) + 1u;
            int c = 0;
            for (int j = tid; j < V; j += 256) c += (int)(fkey(rp[j]) >= mid);
            c = blockReduceSum256(c, tid, s_red);
            if (c >= 50) lo = mid; else hi = mid - 1u;
        }
        unsigned gl = (lo > 2u) ? lo - 2u : 0u;
        __syncthreads();
        if (tid == 0) s_c = 0;
        __syncthreads();
        for (int j = tid; j < V; j += 256) {
            float v = rp[j];
            if (fkey(v) >= gl) {
                int p = atomicAdd(&s_c, 1);
                if (p < CAPROW) { cX[p] = v / 0.8f; cI[p] = j; }
            }
        }
        __syncthreads();
        cnt = min(s_c, CAPROW);
    }

    if (tid < TOP_CAP) { sVal[tid] = -3.4e38f; sIdx[tid] = 0x7FFFFFFF; }
    __syncthreads();

    // Rank-sort: (x desc, token idx asc); LDS broadcast reads conflict-free.
    {
        float v0 = -3.4e38f, v1 = -3.4e38f;
        int i0 = 0x7FFFFFFF, i1 = 0x7FFFFFFF;
        if (tid < cnt) { v0 = cX[tid]; i0 = cI[tid]; }
        if (tid + 256 < cnt) { v1 = cX[tid + 256]; i1 = cI[tid + 256]; }
        int r0 = 0, r1 = 0;
        for (int j = 0; j < cnt; ++j) {
            float w = cX[j];
            int wi = cI[j];
            r0 += (w > v0) || (w == v0 && wi < i0);
            r1 += (w > v1) || (w == v1 && wi < i1);
        }
        if (tid < cnt && r0 < TOP_CAP) { sVal[r0] = v0; sIdx[r0] = i0; }
        if (tid + 256 < cnt && r1 < TOP_CAP) { sVal[r1] = v1; sIdx[r1] = i1; }
    }
    __syncthreads();

    if (tid == 0) {
        float kth = sVal[49];
        int M = 50;
        while (M < TOP_CAP && sVal[M] == kth) ++M;   // include exact ties at kth
        s_M = M;
    }
    __syncthreads();
    int M = s_M;
    if (tid < M) sExp[tid] = exp((double)sVal[tid] - (double)sVal[0]);
    __syncthreads();
    if (tid == 0) {
        double denom = 0.0;
        for (int i = 0; i < M; ++i) denom += sExp[i];
        double cum = 0.0;
        int J = M - 1;
        for (int i = 0; i < M; ++i) {
            cum += sExp[i] / denom;
            if (cum > 0.9) { J = i; break; }
        }
        s_t = sVal[J];
        s_ti = sIdx[J];
    }

    const bool pen = (row & 7) == 7;
    if (pen) {
        __syncthreads();
        for (int w = tid; w < MASK_WORDS_PER_B; w += 256) presRow[w] = 0u;
        __syncthreads();
        const int* bp = ids + (row >> 3) * L_;
#pragma unroll
        for (int k = 0; k < L_ / 256; ++k) {
            int t = bp[k * 256 + tid];
            atomicOr(&presRow[t >> 5], 1u << (t & 31));
        }
    }
    __syncthreads();

    // scatter kept values over bg_kernel's background (ordered by kernel launch)
    float t = s_t;
    int tie = s_ti;
    float* orow = out + (size_t)row * V;
    for (int j = tid; j < cnt; j += 256) {
        float x = cX[j];
        int tok = cI[j];
        bool keep = (x > t) || (x == t && tok <= tie);
        if (keep) {
            float oo = x;   // exact v/0.8f, matches reference bits
            if (pen && ((presRow[tok >> 5] >> (tok & 31)) & 1u))
                oo = (oo < 0.0f) ? oo * 1.2f : oo * (1.0f / 1.2f);
            orow[tok] = oo;
        }
    }
}

// ---------------- safety fallback (ws too small; proven 3-kernel path) ----------------
#define CAND_CAP 4096
#define RT_THREADS 1024

__global__ __launch_bounds__(256) void mask_only_kernel(const int* __restrict__ ids,
                                                        unsigned* __restrict__ mask) {
    const int tid = threadIdx.x;
    const int b = blockIdx.x;
    __shared__ unsigned lds[MASK_WORDS_PER_B];
    for (int w = tid; w < MASK_WORDS_PER_B; w += 256) lds[w] = 0u;
    __syncthreads();
    const int* bp = ids + b * L_;
#pragma unroll
    for (int k = 0; k < L_ / 256; ++k) {
        int t = bp[k * 256 + tid];
        atomicOr(&lds[t >> 5], 1u << (t & 31));
    }
    __syncthreads();
    unsigned* mp = mask + b * MASK_WORDS_PER_B;
    for (int w = tid; w < MASK_WORDS_PER_B; w += 256) mp[w] = lds[w];
}

__global__ __launch_bounds__(RT_THREADS, 8) void row_thresh_kernel(
        const float* __restrict__ logits, uint4* __restrict__ rowParam) {
    const int tid = threadIdx.x;
    const int row = blockIdx.x;
    if (row >= ROWS) return;
    const float* rp = logits + (size_t)row * V;

    __shared__ float candV[CAND_CAP];
    __shared__ int   candI[CAND_CAP];
    __shared__ float sVal[TOP_CAP];
    __shared__ int   sIdx[TOP_CAP];
    __shared__ double sExp[TOP_CAP];
    __shared__ int s_cnt, s_M;
    __shared__ int s_red[RT_THREADS / 64];

    const unsigned mis = (unsigned)(((size_t)row * (size_t)V) & 3u);
    const int a0 = (int)((4u - mis) & 3u);
    const int nv = (V - a0) >> 2;
    const int tailStart = a0 + (nv << 2);
    const float4* vp = reinterpret_cast<const float4*>(rp + a0);

    float TR = 2.4f;
    int cnt = 0;
    for (int attempt = 0; attempt < 12; ++attempt) {
        if (tid == 0) s_cnt = 0;
        __syncthreads();
        for (int base = tid; base < nv; base += 4 * RT_THREADS) {
            int i1 = base + RT_THREADS, i2 = base + 2 * RT_THREADS, i3 = base + 3 * RT_THREADS;
            float4 a = vp[base];
            float4 b = vp[i1 < nv ? i1 : nv - 1];
            float4 c = vp[i2 < nv ? i2 : nv - 1];
            float4 d = vp[i3 < nv ? i3 : nv - 1];
            float va[16] = {a.x, a.y, a.z, a.w, b.x, b.y, b.z, b.w,
                            c.x, c.y, c.z, c.w, d.x, d.y, d.z, d.w};
            int ib[4] = {base, i1, i2, i3};
            bool ok[4] = {true, i1 < nv, i2 < nv, i3 < nv};
#pragma unroll
            for (int q = 0; q < 4; ++q) {
                if (!ok[q]) continue;
#pragma unroll
                for (int cc = 0; cc < 4; ++cc) {
                    float v = va[q * 4 + cc];
                    if (v >= TR) {
                        int p = atomicAdd(&s_cnt, 1);
                        if (p < CAND_CAP) { candV[p] = v / 0.8f; candI[p] = a0 + (ib[q] << 2) + cc; }
                    }
                }
            }
        }
        if (tid < a0) {
            float v = rp[tid];
            if (v >= TR) {
                int p = atomicAdd(&s_cnt, 1);
                if (p < CAND_CAP) { candV[p] = v / 0.8f; candI[p] = tid; }
            }
        }
        if (tid < V - tailStart) {
            float v = rp[tailStart + tid];
            if (v >= TR) {
                int p = atomicAdd(&s_cnt, 1);
                if (p < CAND_CAP) { candV[p] = v / 0.8f; candI[p] = tailStart + tid; }
            }
        }
        __syncthreads();
        cnt = s_cnt;
        if (cnt >= 50 && cnt <= CAND_CAP) break;
        if (cnt < 50) TR -= 1.2f; else TR += 1.2f;
        __syncthreads();
    }
    if (cnt > CAND_CAP) cnt = CAND_CAP;

    if (tid < TOP_CAP) { sVal[tid] = -3.4e38f; sIdx[tid] = 0x7FFFFFFF; }
    __syncthreads();

    {
        float v0 = (tid < cnt) ? candV[tid] : -3.4e38f;
        int i0 = (tid < cnt) ? candI[tid] : 0x7FFFFFFF;
        float v1 = (tid + RT_THREADS < cnt) ? candV[tid + RT_THREADS] : -3.4e38f;
        int i1 = (tid + RT_THREADS < cnt) ? candI[tid + RT_THREADS] : 0x7FFFFFFF;
        float v2 = (tid + 2 * RT_THREADS < cnt) ? candV[tid + 2 * RT_THREADS] : -3.4e38f;
        int i2 = (tid + 2 * RT_THREADS < cnt) ? candI[tid + 2 * RT_THREADS] : 0x7FFFFFFF;
        float v3 = (tid + 3 * RT_THREADS < cnt) ? candV[tid + 3 * RT_THREADS] : -3.4e38f;
        int i3 = (tid + 3 * RT_THREADS < cnt) ? candI[tid + 3 * RT_THREADS] : 0x7FFFFFFF;
        int r0 = 0, r1 = 0, r2 = 0, r3 = 0;
        for (int j = 0; j < cnt; ++j) {
            float w = candV[j];
            int wi = candI[j];
            r0 += (w > v0) || (w == v0 && wi < i0);
            r1 += (w > v1) || (w == v1 && wi < i1);
            r2 += (w > v2) || (w == v2 && wi < i2);
            r3 += (w > v3) || (w == v3 && wi < i3);
        }
        if (tid < cnt && r0 < TOP_CAP) { sVal[r0] = v0; sIdx[r0] = i0; }
        if (tid + RT_THREADS < cnt && r1 < TOP_CAP) { sVal[r1] = v1; sIdx[r1] = i1; }
        if (tid + 2 * RT_THREADS < cnt && r2 < TOP_CAP) { sVal[r2] = v2; sIdx[r2] = i2; }
        if (tid + 3 * RT_THREADS < cnt && r3 < TOP_CAP) { sVal[r3] = v3; sIdx[r3] = i3; }
    }
    __syncthreads();

    if (tid == 0) {
        float kth = sVal[49];
        int M = 50;
        while (M < TOP_CAP && sVal[M] == kth) ++M;
        s_M = M;
    }
    __syncthreads();
    int M = s_M;
    if (tid < M) sExp[tid] = exp((double)sVal[tid] - (double)sVal[0]);
    __syncthreads();

    if (tid == 0) {
        double denom = 0.0;
#pragma unroll 1
        for (int i = 0; i < M; ++i) denom += sExp[i];
        double cum = 0.0;
        int J = M - 1;
#pragma unroll 1
        for (int i = 0; i < M; ++i) {
            cum += sExp[i] / denom;
            if (cum > 0.9) { J = i; break; }
        }
        float t = sVal[J];
        float w = t * 0.8f;
        unsigned wb = __float_as_uint(w);
        unsigned lo = 0xFFFFFFFFu, hi = 0u;
        for (int d = -4; d <= 4; ++d) {
            unsigned ub = wb + (unsigned)d;
            if (__uint_as_float(ub) / 0.8f == t) { if (ub < lo) lo = ub; if (ub > hi) hi = ub; }
        }
        rowParam[row] = make_uint4(lo, hi, (unsigned)sIdx[J], 0u);
    }
}

__global__ __launch_bounds__(256) void apply_kernel(const float4* __restrict__ in4,
                                                    const uint4* __restrict__ rowParam,
                                                    const unsigned* __restrict__ mask,
                                                    float4* __restrict__ out4) {
    int gid = blockIdx.x * 256 + threadIdx.x;
    int i0 = gid << 1;
    if (i0 >= NVEC) return;
    float4 a = in4[i0];
    float4 b = in4[i0 + 1];
    unsigned e = (unsigned)i0 << 2;
    unsigned row = e / (unsigned)V;
    unsigned tok0 = e - row * (unsigned)V;
    uint4 p0 = rowParam[row];
    bool crosses = (tok0 + 7u >= (unsigned)V);
    uint4 p1 = crosses ? rowParam[row + 1] : p0;
    float xs[8] = {a.x, a.y, a.z, a.w, b.x, b.y, b.z, b.w};
    float o[8];
#pragma unroll
    for (int c = 0; c < 8; ++c) {
        unsigned tok = tok0 + (unsigned)c;
        unsigned r = row;
        uint4 pp = p0;
        if (tok >= (unsigned)V) { tok -= (unsigned)V; r = row + 1u; pp = p1; }
        float v = xs[c];
        float vlo = __uint_as_float(pp.x);
        float vhi = __uint_as_float(pp.y);
        bool keep = (v > vhi) || (v >= vlo && tok <= pp.z);
        float oo = keep ? v * 1.25f : NEG_INF;
        if ((r & 7u) == 7u) {
            unsigned w = mask[(r >> 3) * MASK_WORDS_PER_B + (tok >> 5)];
            if ((w >> (tok & 31u)) & 1u) oo = (oo < 0.0f) ? oo * 1.2f : oo * (1.0f / 1.2f);
        }
        o[c] = oo;
    }
    out4[i0] = make_float4(o[0], o[1], o[2], o[3]);
    out4[i0 + 1] = make_float4(o[4], o[5], o[6], o[7]);
}

extern "C" void kernel_launch(void* const* d_in, const int* in_sizes, int n_in,
                              void* d_out, int out_size, void* d_ws, size_t ws_size,
                              hipStream_t stream) {
    const float* logits = (const float*)d_in[0];
    const int* ids = (const int*)d_in[1];
    float* out = (float*)d_out;

    if (ws_size >= WS_NEED) {
        unsigned* wcnt = (unsigned*)((char*)d_ws + WS_WCNT);
        uint2* gcand = (uint2*)((char*)d_ws + WS_GCAND);
        // A/B completion: round-15 gather (one-shot, proven) + round-16 split
        //   gather (read-only) -> bg (pure write) -> select (threshold+scatter)
        gather_kernel<<<GW_BLOCKS, 256, 0, stream>>>((const float4*)logits, gcand, wcnt);
        bg_kernel<<<BG_BLOCKS, 256, 0, stream>>>(ids, (float4*)out);
        select_kernel<<<ROWS, 256, 0, stream>>>(logits, ids, gcand, wcnt, out);
    } else {
        uint4* rowParam = (uint4*)((char*)d_ws + WS_ROWPARAM);
        unsigned* mask = (unsigned*)((char*)d_ws + WS_MASK);
        mask_only_kernel<<<B_, 256, 0, stream>>>(ids, mask);
        row_thresh_kernel<<<ROWS, RT_THREADS, 0, stream>>>(logits, rowParam);
        apply_kernel<<<(NVEC / 2 + 255) / 256, 256, 0, stream>>>((const float4*)logits, rowParam,
                                                                 mask, (float4*)out);
    }
}

// Round 19
// 58.099 us; speedup vs baseline: 1.0087x; 1.0087x over previous
//
#include <hip/hip_runtime.h>
#include <stdint.h>

#define V 50257
#define B_ 64
#define S_ 8
#define ROWS (B_ * S_)
#define L_ 2048
#define NEG_INF -1000000000.0f
#define PEN_NEG (-1200000000.0f)   // fp32(-1e9 * 1.2f), verified exact match
#define MASK_WORDS_PER_B 1571      // ceil(50257/32)
#define TOTAL (ROWS * V)           // 25,731,584
#define NVEC (TOTAL / 4)           // 6,432,896 (exact)
#define TOP_CAP 64                 // top-k=50 plus headroom for exact ties at kth
#define TRAW 2.8f                  // raw cutoff; E[cnt]=128/row
#define F4L 7                      // float4s per lane
#define WCHUNK_F4 (64 * F4L)       // 448 f4 per wave chunk
#define ELEMS_PER_WAVE (WCHUNK_F4 * 4)   // 1792 (spans <= 2 rows)
#define NWAVES ((NVEC + WCHUNK_F4 - 1) / WCHUNK_F4)   // 14360
#define GW_BLOCKS ((NWAVES + 3) / 4)                  // 3590 (exactly NWAVES/4)
#define WCAP 32                    // per-wave region (mean 9.1, sd 3)
#define CAPROW 512                 // per-row candidate cap in select
#define BG_F4 2048                 // f4 per bg block
#define BG_BLOCKS ((NVEC + BG_F4 - 1) / BG_F4)       // 3142
#define BG_PRESW (BG_F4 * 4 / 32)                    // 256 words
#define GB_TOTAL (GW_BLOCKS + BG_BLOCKS)             // 6732

// ---- workspace layout ----
#define WS_WCNT    0                                   // 14360 u32 -> pad 65536
#define WS_GCAND   65536                               // 14360*32*8 = 3,676,160
#define WS_NEED    (WS_GCAND + (size_t)NWAVES * WCAP * 8)   // ~3.74 MB
// fallback layout (disjoint use; only when ws too small for fast path)
#define WS_ROWPARAM 0                                   // 512 * 16 B
#define WS_MASK     8192                                // 402176 B

__device__ __forceinline__ unsigned fkey(float f) {
    unsigned u = __float_as_uint(f);
    return (u & 0x80000000u) ? ~u : (u | 0x80000000u);
}

__device__ __forceinline__ int blockReduceSum256(int v, int tid, int* s4) {
#pragma unroll
    for (int off = 32; off; off >>= 1) v += __shfl_down(v, off);
    __syncthreads();
    if ((tid & 63) == 0) s4[tid >> 6] = v;
    __syncthreads();
    return s4[0] + s4[1] + s4[2] + s4[3];
}

// ---------------- gb: fused gather (read stream) + bg (write stream) ----------------

// Role-split blocks, interleaved so every CU co-hosts read-waves and
// write-waves: even bid -> gather block, odd bid -> bg block (tail -> gather).
// Gather part = round-15 proven one-shot (7 asm-pinned loads, vmcnt(0),
// register shift-queue, wave prefix-sum, private region, no LDS/atomics).
// Bg part = round-18 proven fill (constant NEG_INF; PEN_NEG via LDS
// range-presence for the at-most-one s==7 row in range).
__global__ __launch_bounds__(256) void gb_kernel(const float4* __restrict__ in4,
                                                 const int* __restrict__ ids,
                                                 float4* __restrict__ out4,
                                                 uint2* __restrict__ gcand,
                                                 unsigned* __restrict__ wcnt) {
    const int bid = blockIdx.x;
    const int tid = threadIdx.x;
    int role, idx;
    if (bid < 2 * BG_BLOCKS) {
        role = bid & 1;              // 0 = gather, 1 = bg
        idx = bid >> 1;
    } else {
        role = 0;
        idx = BG_BLOCKS + (bid - 2 * BG_BLOCKS);
    }

    if (role == 1) {
        // ---- bg: pure write stream ----
        __shared__ unsigned pres[BG_PRESW];
        const int start = idx * BG_F4;
        const int end = min(start + BG_F4, NVEC);
        const unsigned baseE = (unsigned)start << 2;
        const unsigned endE = (unsigned)end << 2;
        unsigned r0 = baseE / (unsigned)V, r1 = (endE - 1u) / (unsigned)V;
        unsigned rl = ((r0 & 7u) == 7u) ? r0 : (((r1 & 7u) == 7u) ? r1 : 0xFFFFFFFFu);
        if (rl == 0xFFFFFFFFu) {
            const float4 bg = make_float4(NEG_INF, NEG_INF, NEG_INF, NEG_INF);
#pragma unroll
            for (int k = 0; k < 8; ++k) {
                int i = start + tid + k * 256;
                if (i < end) out4[i] = bg;
            }
            return;
        }
        for (int w = tid; w < BG_PRESW; w += 256) pres[w] = 0u;
        __syncthreads();
        const int* bp = ids + (rl >> 3) * L_;
        unsigned rowBase = rl * (unsigned)V;
#pragma unroll
        for (int k = 0; k < L_ / 256; ++k) {
            unsigned ge = rowBase + (unsigned)bp[k * 256 + tid];
            if (ge >= baseE && ge < endE) {
                unsigned off = ge - baseE;
                atomicOr(&pres[off >> 5], 1u << (off & 31));
            }
        }
        __syncthreads();
#pragma unroll
        for (int k = 0; k < 8; ++k) {
            int i = start + tid + k * 256;
            if (i < end) {
                unsigned off = ((unsigned)i << 2) - baseE;   // multiple of 4
                unsigned pw = pres[off >> 5] >> (off & 31u);
                float4 bg;
                bg.x = (pw & 1u) ? PEN_NEG : NEG_INF;
                bg.y = (pw & 2u) ? PEN_NEG : NEG_INF;
                bg.z = (pw & 4u) ? PEN_NEG : NEG_INF;
                bg.w = (pw & 8u) ? PEN_NEG : NEG_INF;
                out4[i] = bg;
            }
        }
        return;
    }

    // ---- gather: pure read stream (round-15 one-shot) ----
    const int wid = idx * 4 + (tid >> 6);
    if (wid >= NWAVES) return;
    const int lane = tid & 63;
    const int b = wid * WCHUNK_F4 + lane;

    const float4* p0 = in4 + min(b,          NVEC - 1);
    const float4* p1 = in4 + min(b + 64,     NVEC - 1);
    const float4* p2 = in4 + min(b + 2 * 64, NVEC - 1);
    const float4* p3 = in4 + min(b + 3 * 64, NVEC - 1);
    const float4* p4 = in4 + min(b + 4 * 64, NVEC - 1);
    const float4* p5 = in4 + min(b + 5 * 64, NVEC - 1);
    const float4* p6 = in4 + min(b + 6 * 64, NVEC - 1);

    float4 va0, va1, va2, va3, va4, va5, va6;
#define LOADPIN(dst, src)                                                     \
    asm volatile("global_load_dwordx4 %0, %1, off" : "=v"(dst) : "v"(src));   \
    __builtin_amdgcn_sched_barrier(0);
    LOADPIN(va0, p0) LOADPIN(va1, p1) LOADPIN(va2, p2) LOADPIN(va3, p3)
    LOADPIN(va4, p4) LOADPIN(va5, p5) LOADPIN(va6, p6)
#undef LOADPIN
    asm volatile("s_waitcnt vmcnt(0)" ::: "memory");
    __builtin_amdgcn_sched_barrier(0);

    float q0v = 0.f, q1v = 0.f, q2v = 0.f, q3v = 0.f, q4v = 0.f, q5v = 0.f, q6v = 0.f, q7v = 0.f;
    int q0i = 0, q1i = 0, q2i = 0, q3i = 0, q4i = 0, q5i = 0, q6i = 0, q7i = 0;
    int nh = 0;

#define INS(val, ei)                                                          \
    if ((val) >= TRAW) {                                                      \
        q7v = q6v; q7i = q6i; q6v = q5v; q6i = q5i; q5v = q4v; q5i = q4i;     \
        q4v = q3v; q4i = q3i; q3v = q2v; q3i = q2i; q2v = q1v; q2i = q1i;     \
        q1v = q0v; q1i = q0i; q0v = (val); q0i = (ei); ++nh;                  \
    }
#define CONSUME(vv, kk)                                                       \
    {                                                                         \
        int i = b + (kk) * 64;                                                \
        if (i < NVEC) {                                                       \
            int e = i << 2;                                                   \
            INS((vv).x, e)                                                    \
            INS((vv).y, e + 1)                                                \
            INS((vv).z, e + 2)                                                \
            INS((vv).w, e + 3)                                                \
        }                                                                     \
    }
    CONSUME(va0, 0) CONSUME(va1, 1) CONSUME(va2, 2) CONSUME(va3, 3)
    CONSUME(va4, 4) CONSUME(va5, 5) CONSUME(va6, 6)
#undef CONSUME
#undef INS

    int m = nh > 8 ? 8 : nh;
    int incl = m;
#pragma unroll
    for (int d = 1; d < 64; d <<= 1) {
        int t = __shfl_up(incl, d);
        if (lane >= d) incl += t;
    }
    int excl = incl - m;
    int total = __shfl(incl, 63);
    bool of = (total > WCAP) || __any(nh > 8);

    size_t rb = (size_t)wid * WCAP;
    if (m >= 1 && excl + 0 < WCAP) gcand[rb + excl + 0] = make_uint2((unsigned)q0i, __float_as_uint(q0v));
    if (m >= 2 && excl + 1 < WCAP) gcand[rb + excl + 1] = make_uint2((unsigned)q1i, __float_as_uint(q1v));
    if (m >= 3 && excl + 2 < WCAP) gcand[rb + excl + 2] = make_uint2((unsigned)q2i, __float_as_uint(q2v));
    if (m >= 4 && excl + 3 < WCAP) gcand[rb + excl + 3] = make_uint2((unsigned)q3i, __float_as_uint(q3v));
    if (m >= 5 && excl + 4 < WCAP) gcand[rb + excl + 4] = make_uint2((unsigned)q4i, __float_as_uint(q4v));
    if (m >= 6 && excl + 5 < WCAP) gcand[rb + excl + 5] = make_uint2((unsigned)q5i, __float_as_uint(q5v));
    if (m >= 7 && excl + 6 < WCAP) gcand[rb + excl + 6] = make_uint2((unsigned)q6i, __float_as_uint(q6v));
    if (m >= 8 && excl + 7 < WCAP) gcand[rb + excl + 7] = make_uint2((unsigned)q7i, __float_as_uint(q7v));
    if (lane == 0) wcnt[wid] = of ? 1000000u : (unsigned)total;
}

// ---------------- select: exact threshold + kept-value scatter only ----------------

// One 256-thread block per row. Exact reference semantics incl. fp32 ties
// (validated absmax=0): kth = 50th largest of x=v/0.8f; kept = ALL x >= kth;
// stable (x desc, idx asc) order; f64 softmax+cumsum decision. Background is
// already written by gb_kernel; scatter only the ~50 kept values.
__global__ __launch_bounds__(256) void select_kernel(const float* __restrict__ logits,
                                                     const int* __restrict__ ids,
                                                     const uint2* __restrict__ gcand,
                                                     const unsigned* __restrict__ wcnt,
                                                     float* __restrict__ out) {
    const int row = blockIdx.x;
    const int tid = threadIdx.x;
    __shared__ float cX[CAPROW];
    __shared__ int cI[CAPROW];
    __shared__ float sVal[TOP_CAP];
    __shared__ int sIdx[TOP_CAP];
    __shared__ double sExp[TOP_CAP];
    __shared__ unsigned presRow[MASK_WORDS_PER_B];
    __shared__ unsigned s_wc[40];
    __shared__ int s_c, s_M, s_bad, s_ti;
    __shared__ float s_t;
    __shared__ int s_red[4];

    const float* rp = logits + (size_t)row * V;
    const unsigned e0 = (unsigned)row * (unsigned)V;
    if (tid == 0) { s_c = 0; s_bad = 0; }
    __syncthreads();

    {   // flat parallel scan of the ~29 wave-regions overlapping this row
        const int r0 = (int)(e0 / (unsigned)ELEMS_PER_WAVE);
        const int r1 = (int)((e0 + V - 1) / (unsigned)ELEMS_PER_WAVE);
        const int nr = r1 - r0 + 1;                 // <= 30
        if (tid < nr) s_wc[tid] = wcnt[r0 + tid];
        __syncthreads();
        const int nslots = nr * WCAP;
        for (int j = tid; j < nslots; j += 256) {
            int r = j >> 5;                          // WCAP = 32
            int sl = j & 31;
            unsigned c = s_wc[r];
            if (c > (unsigned)WCAP) { s_bad = 1; c = WCAP; }   // benign race
            if (sl < (int)c) {
                uint2 u = gcand[(size_t)(r0 + r) * WCAP + sl];
                if (u.x / (unsigned)V == (unsigned)row) {
                    int p = atomicAdd(&s_c, 1);
                    if (p < CAPROW) {
                        cX[p] = __uint_as_float(u.y) / 0.8f;
                        cI[p] = (int)(u.x - e0);
                    }
                }
            }
        }
    }
    __syncthreads();
    int cnt = s_c;
    if (s_bad || cnt < 50 || cnt > CAPROW) {
        // Pathological-only exact fallback: bisect raw key space for the 50th
        // largest, re-gather with 2-ulp slack.
        unsigned lo = 0u, hi = 0xFFFFFFFFu;
        while (lo < hi) {
            unsigned mid = lo + ((hi - lo) >> 1) + 1u;
            int c = 0;
            for (int j = tid; j < V; j += 256) c += (int)(fkey(rp[j]) >= mid);
            c = blockReduceSum256(c, tid, s_red);
            if (c >= 50) lo = mid; else hi = mid - 1u;
        }
        unsigned gl = (lo > 2u) ? lo - 2u : 0u;
        __syncthreads();
        if (tid == 0) s_c = 0;
        __syncthreads();
        for (int j = tid; j < V; j += 256) {
            float v = rp[j];
            if (fkey(v) >= gl) {
                int p = atomicAdd(&s_c, 1);
                if (p < CAPROW) { cX[p] = v / 0.8f; cI[p] = j; }
            }
        }
        __syncthreads();
        cnt = min(s_c, CAPROW);
    }

    if (tid < TOP_CAP) { sVal[tid] = -3.4e38f; sIdx[tid] = 0x7FFFFFFF; }
    __syncthreads();

    // Rank-sort: (x desc, token idx asc); LDS broadcast reads conflict-free.
    {
        float v0 = -3.4e38f, v1 = -3.4e38f;
        int i0 = 0x7FFFFFFF, i1 = 0x7FFFFFFF;
        if (tid < cnt) { v0 = cX[tid]; i0 = cI[tid]; }
        if (tid + 256 < cnt) { v1 = cX[tid + 256]; i1 = cI[tid + 256]; }
        int r0 = 0, r1 = 0;
        for (int j = 0; j < cnt; ++j) {
            float w = cX[j];
            int wi = cI[j];
            r0 += (w > v0) || (w == v0 && wi < i0);
            r1 += (w > v1) || (w == v1 && wi < i1);
        }
        if (tid < cnt && r0 < TOP_CAP) { sVal[r0] = v0; sIdx[r0] = i0; }
        if (tid + 256 < cnt && r1 < TOP_CAP) { sVal[r1] = v1; sIdx[r1] = i1; }
    }
    __syncthreads();

    if (tid == 0) {
        float kth = sVal[49];
        int M = 50;
        while (M < TOP_CAP && sVal[M] == kth) ++M;   // include exact ties at kth
        s_M = M;
    }
    __syncthreads();
    int M = s_M;
    if (tid < M) sExp[tid] = exp((double)sVal[tid] - (double)sVal[0]);
    __syncthreads();
    if (tid == 0) {
        double denom = 0.0;
        for (int i = 0; i < M; ++i) denom += sExp[i];
        double cum = 0.0;
        int J = M - 1;
        for (int i = 0; i < M; ++i) {
            cum += sExp[i] / denom;
            if (cum > 0.9) { J = i; break; }
        }
        s_t = sVal[J];
        s_ti = sIdx[J];
    }

    const bool pen = (row & 7) == 7;
    if (pen) {
        __syncthreads();
        for (int w = tid; w < MASK_WORDS_PER_B; w += 256) presRow[w] = 0u;
        __syncthreads();
        const int* bp = ids + (row >> 3) * L_;
#pragma unroll
        for (int k = 0; k < L_ / 256; ++k) {
            int t = bp[k * 256 + tid];
            atomicOr(&presRow[t >> 5], 1u << (t & 31));
        }
    }
    __syncthreads();

    // scatter kept values over gb_kernel's background (ordered by kernel launch)
    float t = s_t;
    int tie = s_ti;
    float* orow = out + (size_t)row * V;
    for (int j = tid; j < cnt; j += 256) {
        float x = cX[j];
        int tok = cI[j];
        bool keep = (x > t) || (x == t && tok <= tie);
        if (keep) {
            float oo = x;   // exact v/0.8f, matches reference bits
            if (pen && ((presRow[tok >> 5] >> (tok & 31)) & 1u))
                oo = (oo < 0.0f) ? oo * 1.2f : oo * (1.0f / 1.2f);
            orow[tok] = oo;
        }
    }
}

// ---------------- safety fallback (ws too small; proven 3-kernel path) ----------------
#define CAND_CAP 4096
#define RT_THREADS 1024

__global__ __launch_bounds__(256) void mask_only_kernel(const int* __restrict__ ids,
                                                        unsigned* __restrict__ mask) {
    const int tid = threadIdx.x;
    const int b = blockIdx.x;
    __shared__ unsigned lds[MASK_WORDS_PER_B];
    for (int w = tid; w < MASK_WORDS_PER_B; w += 256) lds[w] = 0u;
    __syncthreads();
    const int* bp = ids + b * L_;
#pragma unroll
    for (int k = 0; k < L_ / 256; ++k) {
        int t = bp[k * 256 + tid];
        atomicOr(&lds[t >> 5], 1u << (t & 31));
    }
    __syncthreads();
    unsigned* mp = mask + b * MASK_WORDS_PER_B;
    for (int w = tid; w < MASK_WORDS_PER_B; w += 256) mp[w] = lds[w];
}

__global__ __launch_bounds__(RT_THREADS, 8) void row_thresh_kernel(
        const float* __restrict__ logits, uint4* __restrict__ rowParam) {
    const int tid = threadIdx.x;
    const int row = blockIdx.x;
    if (row >= ROWS) return;
    const float* rp = logits + (size_t)row * V;

    __shared__ float candV[CAND_CAP];
    __shared__ int   candI[CAND_CAP];
    __shared__ float sVal[TOP_CAP];
    __shared__ int   sIdx[TOP_CAP];
    __shared__ double sExp[TOP_CAP];
    __shared__ int s_cnt, s_M;
    __shared__ int s_red[RT_THREADS / 64];

    const unsigned mis = (unsigned)(((size_t)row * (size_t)V) & 3u);
    const int a0 = (int)((4u - mis) & 3u);
    const int nv = (V - a0) >> 2;
    const int tailStart = a0 + (nv << 2);
    const float4* vp = reinterpret_cast<const float4*>(rp + a0);

    float TR = 2.4f;
    int cnt = 0;
    for (int attempt = 0; attempt < 12; ++attempt) {
        if (tid == 0) s_cnt = 0;
        __syncthreads();
        for (int base = tid; base < nv; base += 4 * RT_THREADS) {
            int i1 = base + RT_THREADS, i2 = base + 2 * RT_THREADS, i3 = base + 3 * RT_THREADS;
            float4 a = vp[base];
            float4 b = vp[i1 < nv ? i1 : nv - 1];
            float4 c = vp[i2 < nv ? i2 : nv - 1];
            float4 d = vp[i3 < nv ? i3 : nv - 1];
            float va[16] = {a.x, a.y, a.z, a.w, b.x, b.y, b.z, b.w,
                            c.x, c.y, c.z, c.w, d.x, d.y, d.z, d.w};
            int ib[4] = {base, i1, i2, i3};
            bool ok[4] = {true, i1 < nv, i2 < nv, i3 < nv};
#pragma unroll
            for (int q = 0; q < 4; ++q) {
                if (!ok[q]) continue;
#pragma unroll
                for (int cc = 0; cc < 4; ++cc) {
                    float v = va[q * 4 + cc];
                    if (v >= TR) {
                        int p = atomicAdd(&s_cnt, 1);
                        if (p < CAND_CAP) { candV[p] = v / 0.8f; candI[p] = a0 + (ib[q] << 2) + cc; }
                    }
                }
            }
        }
        if (tid < a0) {
            float v = rp[tid];
            if (v >= TR) {
                int p = atomicAdd(&s_cnt, 1);
                if (p < CAND_CAP) { candV[p] = v / 0.8f; candI[p] = tid; }
            }
        }
        if (tid < V - tailStart) {
            float v = rp[tailStart + tid];
            if (v >= TR) {
                int p = atomicAdd(&s_cnt, 1);
                if (p < CAND_CAP) { candV[p] = v / 0.8f; candI[p] = tailStart + tid; }
            }
        }
        __syncthreads();
        cnt = s_cnt;
        if (cnt >= 50 && cnt <= CAND_CAP) break;
        if (cnt < 50) TR -= 1.2f; else TR += 1.2f;
        __syncthreads();
    }
    if (cnt > CAND_CAP) cnt = CAND_CAP;

    if (tid < TOP_CAP) { sVal[tid] = -3.4e38f; sIdx[tid] = 0x7FFFFFFF; }
    __syncthreads();

    {
        float v0 = (tid < cnt) ? candV[tid] : -3.4e38f;
        int i0 = (tid < cnt) ? candI[tid] : 0x7FFFFFFF;
        float v1 = (tid + RT_THREADS < cnt) ? candV[tid + RT_THREADS] : -3.4e38f;
        int i1 = (tid + RT_THREADS < cnt) ? candI[tid + RT_THREADS] : 0x7FFFFFFF;
        float v2 = (tid + 2 * RT_THREADS < cnt) ? candV[tid + 2 * RT_THREADS] : -3.4e38f;
        int i2 = (tid + 2 * RT_THREADS < cnt) ? candI[tid + 2 * RT_THREADS] : 0x7FFFFFFF;
        float v3 = (tid + 3 * RT_THREADS < cnt) ? candV[tid + 3 * RT_THREADS] : -3.4e38f;
        int i3 = (tid + 3 * RT_THREADS < cnt) ? candI[tid + 3 * RT_THREADS] : 0x7FFFFFFF;
        int r0 = 0, r1 = 0, r2 = 0, r3 = 0;
        for (int j = 0; j < cnt; ++j) {
            float w = candV[j];
            int wi = candI[j];
            r0 += (w > v0) || (w == v0 && wi < i0);
            r1 += (w > v1) || (w == v1 && wi < i1);
            r2 += (w > v2) || (w == v2 && wi < i2);
            r3 += (w > v3) || (w == v3 && wi < i3);
        }
        if (tid < cnt && r0 < TOP_CAP) { sVal[r0] = v0; sIdx[r0] = i0; }
        if (tid + RT_THREADS < cnt && r1 < TOP_CAP) { sVal[r1] = v1; sIdx[r1] = i1; }
        if (tid + 2 * RT_THREADS < cnt && r2 < TOP_CAP) { sVal[r2] = v2; sIdx[r2] = i2; }
        if (tid + 3 * RT_THREADS < cnt && r3 < TOP_CAP) { sVal[r3] = v3; sIdx[r3] = i3; }
    }
    __syncthreads();

    if (tid == 0) {
        float kth = sVal[49];
        int M = 50;
        while (M < TOP_CAP && sVal[M] == kth) ++M;
        s_M = M;
    }
    __syncthreads();
    int M = s_M;
    if (tid < M) sExp[tid] = exp((double)sVal[tid] - (double)sVal[0]);
    __syncthreads();

    if (tid == 0) {
        double denom = 0.0;
#pragma unroll 1
        for (int i = 0; i < M; ++i) denom += sExp[i];
        double cum = 0.0;
        int J = M - 1;
#pragma unroll 1
        for (int i = 0; i < M; ++i) {
            cum += sExp[i] / denom;
            if (cum > 0.9) { J = i; break; }
        }
        float t = sVal[J];
        float w = t * 0.8f;
        unsigned wb = __float_as_uint(w);
        unsigned lo = 0xFFFFFFFFu, hi = 0u;
        for (int d = -4; d <= 4; ++d) {
            unsigned ub = wb + (unsigned)d;
            if (__uint_as_float(ub) / 0.8f == t) { if (ub < lo) lo = ub; if (ub > hi) hi = ub; }
        }
        rowParam[row] = make_uint4(lo, hi, (unsigned)sIdx[J], 0u);
    }
}

__global__ __launch_bounds__(256) void apply_kernel(const float4* __restrict__ in4,
                                                    const uint4* __restrict__ rowParam,
                                                    const unsigned* __restrict__ mask,
                                                    float4* __restrict__ out4) {
    int gid = blockIdx.x * 256 + threadIdx.x;
    int i0 = gid << 1;
    if (i0 >= NVEC) return;
    float4 a = in4[i0];
    float4 b = in4[i0 + 1];
    unsigned e = (unsigned)i0 << 2;
    unsigned row = e / (unsigned)V;
    unsigned tok0 = e - row * (unsigned)V;
    uint4 p0 = rowParam[row];
    bool crosses = (tok0 + 7u >= (unsigned)V);
    uint4 p1 = crosses ? rowParam[row + 1] : p0;
    float xs[8] = {a.x, a.y, a.z, a.w, b.x, b.y, b.z, b.w};
    float o[8];
#pragma unroll
    for (int c = 0; c < 8; ++c) {
        unsigned tok = tok0 + (unsigned)c;
        unsigned r = row;
        uint4 pp = p0;
        if (tok >= (unsigned)V) { tok -= (unsigned)V; r = row + 1u; pp = p1; }
        float v = xs[c];
        float vlo = __uint_as_float(pp.x);
        float vhi = __uint_as_float(pp.y);
        bool keep = (v > vhi) || (v >= vlo && tok <= pp.z);
        float oo = keep ? v * 1.25f : NEG_INF;
        if ((r & 7u) == 7u) {
            unsigned w = mask[(r >> 3) * MASK_WORDS_PER_B + (tok >> 5)];
            if ((w >> (tok & 31u)) & 1u) oo = (oo < 0.0f) ? oo * 1.2f : oo * (1.0f / 1.2f);
        }
        o[c] = oo;
    }
    out4[i0] = make_float4(o[0], o[1], o[2], o[3]);
    out4[i0 + 1] = make_float4(o[4], o[5], o[6], o[7]);
}

extern "C" void kernel_launch(void* const* d_in, const int* in_sizes, int n_in,
                              void* d_out, int out_size, void* d_ws, size_t ws_size,
                              hipStream_t stream) {
    const float* logits = (const float*)d_in[0];
    const int* ids = (const int*)d_in[1];
    float* out = (float*)d_out;

    if (ws_size >= WS_NEED) {
        unsigned* wcnt = (unsigned*)((char*)d_ws + WS_WCNT);
        uint2* gcand = (uint2*)((char*)d_ws + WS_GCAND);
        // 2-kernel fast path: gb (fused read-gather + write-background,
        // role-interleaved blocks so both streams co-reside on each CU)
        // -> select (exact threshold + kept-value scatter)
        gb_kernel<<<GB_TOTAL, 256, 0, stream>>>((const float4*)logits, ids, (float4*)out,
                                                gcand, wcnt);
        select_kernel<<<ROWS, 256, 0, stream>>>(logits, ids, gcand, wcnt, out);
    } else {
        uint4* rowParam = (uint4*)((char*)d_ws + WS_ROWPARAM);
        unsigned* mask = (unsigned*)((char*)d_ws + WS_MASK);
        mask_only_kernel<<<B_, 256, 0, stream>>>(ids, mask);
        row_thresh_kernel<<<ROWS, RT_THREADS, 0, stream>>>(logits, rowParam);
        apply_kernel<<<(NVEC / 2 + 255) / 256, 256, 0, stream>>>((const float4*)logits, rowParam,
                                                                 mask, (float4*)out);
    }
}

// Round 20
// 56.939 us; speedup vs baseline: 1.0292x; 1.0204x over previous
//
#include <hip/hip_runtime.h>
#include <stdint.h>

#define V 50257
#define B_ 64
#define S_ 8
#define ROWS (B_ * S_)
#define L_ 2048
#define NEG_INF -1000000000.0f
#define PEN_NEG (-1200000000.0f)   // fp32(-1e9 * 1.2f), verified exact match
#define MASK_WORDS_PER_B 1571      // ceil(50257/32)
#define TOTAL (ROWS * V)           // 25,731,584
#define NVEC (TOTAL / 4)           // 6,432,896 (exact)
#define TOP_CAP 64                 // top-k=50 plus headroom for exact ties at kth
#define TRAW 2.8f                  // raw cutoff; E[cnt]=128/row
#define F4L 7                      // float4s per lane
#define WCHUNK_F4 (64 * F4L)       // 448 f4 per wave chunk
#define ELEMS_PER_WAVE (WCHUNK_F4 * 4)   // 1792 (spans <= 2 rows)
#define NWAVES ((NVEC + WCHUNK_F4 - 1) / WCHUNK_F4)   // 14360
#define GW_BLOCKS ((NWAVES + 3) / 4)                  // 3590
#define WCAP 32                    // per-wave region (mean 9.1, sd 3)
#define CAPROW 512                 // per-row candidate cap in select
#define SEL_T 1024                 // select block size (32 waves/CU during write)

// ---- workspace layout ----
#define WS_WCNT    0                                   // 14360 u32 -> pad 65536
#define WS_GCAND   65536                               // 14360*32*8 = 3,676,160
#define WS_NEED    (WS_GCAND + (size_t)NWAVES * WCAP * 8)   // ~3.74 MB
// fallback layout (disjoint use; only when ws too small for fast path)
#define WS_ROWPARAM 0                                   // 512 * 16 B
#define WS_MASK     8192                                // 402176 B

__device__ __forceinline__ unsigned fkey(float f) {
    unsigned u = __float_as_uint(f);
    return (u & 0x80000000u) ? ~u : (u | 0x80000000u);
}

__device__ __forceinline__ int blockReduceSum1024v(int v, int tid, int* s16) {
#pragma unroll
    for (int off = 32; off; off >>= 1) v += __shfl_down(v, off);
    __syncthreads();
    if ((tid & 63) == 0) s16[tid >> 6] = v;
    __syncthreads();
    int t = 0;
#pragma unroll
    for (int k = 0; k < SEL_T / 64; ++k) t += s16[k];
    return t;
}

// ---------------- gather: per-wave one-shot (round-15 proven, byte-identical) ----------------

__global__ __launch_bounds__(256) void gather_kernel(const float4* __restrict__ in4,
                                                     uint2* __restrict__ gcand,
                                                     unsigned* __restrict__ wcnt) {
    const int wid = blockIdx.x * 4 + (threadIdx.x >> 6);
    if (wid >= NWAVES) return;
    const int lane = threadIdx.x & 63;
    const int b = wid * WCHUNK_F4 + lane;

    const float4* p0 = in4 + min(b,          NVEC - 1);
    const float4* p1 = in4 + min(b + 64,     NVEC - 1);
    const float4* p2 = in4 + min(b + 2 * 64, NVEC - 1);
    const float4* p3 = in4 + min(b + 3 * 64, NVEC - 1);
    const float4* p4 = in4 + min(b + 4 * 64, NVEC - 1);
    const float4* p5 = in4 + min(b + 5 * 64, NVEC - 1);
    const float4* p6 = in4 + min(b + 6 * 64, NVEC - 1);

    float4 va0, va1, va2, va3, va4, va5, va6;
#define LOADPIN(dst, src)                                                     \
    asm volatile("global_load_dwordx4 %0, %1, off" : "=v"(dst) : "v"(src));   \
    __builtin_amdgcn_sched_barrier(0);
    LOADPIN(va0, p0) LOADPIN(va1, p1) LOADPIN(va2, p2) LOADPIN(va3, p3)
    LOADPIN(va4, p4) LOADPIN(va5, p5) LOADPIN(va6, p6)
#undef LOADPIN
    asm volatile("s_waitcnt vmcnt(0)" ::: "memory");
    __builtin_amdgcn_sched_barrier(0);

    float q0v = 0.f, q1v = 0.f, q2v = 0.f, q3v = 0.f, q4v = 0.f, q5v = 0.f, q6v = 0.f, q7v = 0.f;
    int q0i = 0, q1i = 0, q2i = 0, q3i = 0, q4i = 0, q5i = 0, q6i = 0, q7i = 0;
    int nh = 0;

#define INS(val, ei)                                                          \
    if ((val) >= TRAW) {                                                      \
        q7v = q6v; q7i = q6i; q6v = q5v; q6i = q5i; q5v = q4v; q5i = q4i;     \
        q4v = q3v; q4i = q3i; q3v = q2v; q3i = q2i; q2v = q1v; q2i = q1i;     \
        q1v = q0v; q1i = q0i; q0v = (val); q0i = (ei); ++nh;                  \
    }
#define CONSUME(vv, kk)                                                       \
    {                                                                         \
        int i = b + (kk) * 64;                                                \
        if (i < NVEC) {                                                       \
            int e = i << 2;                                                   \
            INS((vv).x, e)                                                    \
            INS((vv).y, e + 1)                                                \
            INS((vv).z, e + 2)                                                \
            INS((vv).w, e + 3)                                                \
        }                                                                     \
    }
    CONSUME(va0, 0) CONSUME(va1, 1) CONSUME(va2, 2) CONSUME(va3, 3)
    CONSUME(va4, 4) CONSUME(va5, 5) CONSUME(va6, 6)
#undef CONSUME
#undef INS

    int m = nh > 8 ? 8 : nh;
    int incl = m;
#pragma unroll
    for (int d = 1; d < 64; d <<= 1) {
        int t = __shfl_up(incl, d);
        if (lane >= d) incl += t;
    }
    int excl = incl - m;
    int total = __shfl(incl, 63);
    bool of = (total > WCAP) || __any(nh > 8);

    size_t rb = (size_t)wid * WCAP;
    if (m >= 1 && excl + 0 < WCAP) gcand[rb + excl + 0] = make_uint2((unsigned)q0i, __float_as_uint(q0v));
    if (m >= 2 && excl + 1 < WCAP) gcand[rb + excl + 1] = make_uint2((unsigned)q1i, __float_as_uint(q1v));
    if (m >= 3 && excl + 2 < WCAP) gcand[rb + excl + 2] = make_uint2((unsigned)q2i, __float_as_uint(q2v));
    if (m >= 4 && excl + 3 < WCAP) gcand[rb + excl + 3] = make_uint2((unsigned)q3i, __float_as_uint(q3v));
    if (m >= 5 && excl + 4 < WCAP) gcand[rb + excl + 4] = make_uint2((unsigned)q4i, __float_as_uint(q4v));
    if (m >= 6 && excl + 5 < WCAP) gcand[rb + excl + 5] = make_uint2((unsigned)q5i, __float_as_uint(q5v));
    if (m >= 7 && excl + 6 < WCAP) gcand[rb + excl + 6] = make_uint2((unsigned)q6i, __float_as_uint(q6v));
    if (m >= 8 && excl + 7 < WCAP) gcand[rb + excl + 7] = make_uint2((unsigned)q7i, __float_as_uint(q7v));
    if (lane == 0) wcnt[wid] = of ? 1000000u : (unsigned)total;
}

// ---------------- select: r15 structure at 1024 threads (4x write issue width) ----------------

// One 1024-thread block per row. Exact reference semantics incl. fp32 ties
// (validated absmax=0): kth = 50th largest of x=v/0.8f; kept = ALL x >= kth;
// stable (x desc, idx asc) order; f64 softmax+cumsum decision. Writes the
// ENTIRE row (background NEG_INF / PEN_NEG via LDS bitmask), barrier (vmcnt
// drained -> stores ordered), then overwrites the ~50 kept tokens.
__global__ __launch_bounds__(SEL_T, 8) void select_kernel(const float* __restrict__ logits,
                                                          const int* __restrict__ ids,
                                                          const uint2* __restrict__ gcand,
                                                          const unsigned* __restrict__ wcnt,
                                                          float* __restrict__ out) {
    const int row = blockIdx.x;
    const int tid = threadIdx.x;
    __shared__ float cX[CAPROW];
    __shared__ int cI[CAPROW];
    __shared__ float sVal[TOP_CAP];
    __shared__ int sIdx[TOP_CAP];
    __shared__ double sExp[TOP_CAP];
    __shared__ unsigned presRow[MASK_WORDS_PER_B];
    __shared__ unsigned s_wc[40];
    __shared__ int s_c, s_M, s_bad, s_ti;
    __shared__ float s_t;
    __shared__ int s_red[SEL_T / 64];

    const float* rp = logits + (size_t)row * V;
    const unsigned e0 = (unsigned)row * (unsigned)V;
    if (tid == 0) { s_c = 0; s_bad = 0; }
    __syncthreads();

    {   // flat parallel scan of the ~29 wave-regions overlapping this row
        const int r0 = (int)(e0 / (unsigned)ELEMS_PER_WAVE);
        const int r1 = (int)((e0 + V - 1) / (unsigned)ELEMS_PER_WAVE);
        const int nr = r1 - r0 + 1;                 // <= 30
        if (tid < nr) s_wc[tid] = wcnt[r0 + tid];
        __syncthreads();
        const int nslots = nr * WCAP;               // <= 960 < SEL_T
        if (tid < nslots) {
            int r = tid >> 5;                        // WCAP = 32
            int sl = tid & 31;
            unsigned c = s_wc[r];
            if (c > (unsigned)WCAP) { s_bad = 1; c = WCAP; }   // benign race
            if (sl < (int)c) {
                uint2 u = gcand[(size_t)(r0 + r) * WCAP + sl];
                if (u.x / (unsigned)V == (unsigned)row) {
                    int p = atomicAdd(&s_c, 1);
                    if (p < CAPROW) {
                        cX[p] = __uint_as_float(u.y) / 0.8f;
                        cI[p] = (int)(u.x - e0);
                    }
                }
            }
        }
    }
    __syncthreads();
    int cnt = s_c;
    if (s_bad || cnt < 50 || cnt > CAPROW) {
        // Pathological-only exact fallback: bisect raw key space for the 50th
        // largest, re-gather with 2-ulp slack.
        unsigned lo = 0u, hi = 0xFFFFFFFFu;
        while (lo < hi) {
            unsigned mid = lo + ((hi - lo) >> 1) + 1u;
            int c = 0;
            for (int j = tid; j < V; j += SEL_T) c += (int)(fkey(rp[j]) >= mid);
            c = blockReduceSum1024v(c, tid, s_red);
            if (c >= 50) lo = mid; else hi = mid - 1u;
        }
        unsigned gl = (lo > 2u) ? lo - 2u : 0u;
        __syncthreads();
        if (tid == 0) s_c = 0;
        __syncthreads();
        for (int j = tid; j < V; j += SEL_T) {
            float v = rp[j];
            if (fkey(v) >= gl) {
                int p = atomicAdd(&s_c, 1);
                if (p < CAPROW) { cX[p] = v / 0.8f; cI[p] = j; }
            }
        }
        __syncthreads();
        cnt = min(s_c, CAPROW);
    }

    if (tid < TOP_CAP) { sVal[tid] = -3.4e38f; sIdx[tid] = 0x7FFFFFFF; }
    __syncthreads();

    // Rank-sort: one candidate per thread (cnt <= 512 < 1024); j-loop is an
    // LDS broadcast read (conflict-free). Key: (x desc, token idx asc).
    {
        float v0 = -3.4e38f;
        int i0 = 0x7FFFFFFF;
        if (tid < cnt) { v0 = cX[tid]; i0 = cI[tid]; }
        int r0 = 0;
        for (int j = 0; j < cnt; ++j) {
            float w = cX[j];
            int wi = cI[j];
            r0 += (w > v0) || (w == v0 && wi < i0);
        }
        if (tid < cnt && r0 < TOP_CAP) { sVal[r0] = v0; sIdx[r0] = i0; }
    }
    __syncthreads();

    if (tid == 0) {
        float kth = sVal[49];
        int M = 50;
        while (M < TOP_CAP && sVal[M] == kth) ++M;   // include exact ties at kth
        s_M = M;
    }
    __syncthreads();
    int M = s_M;
    if (tid < M) sExp[tid] = exp((double)sVal[tid] - (double)sVal[0]);
    __syncthreads();
    if (tid == 0) {
        double denom = 0.0;
        for (int i = 0; i < M; ++i) denom += sExp[i];
        double cum = 0.0;
        int J = M - 1;
        for (int i = 0; i < M; ++i) {
            cum += sExp[i] / denom;
            if (cum > 0.9) { J = i; break; }
        }
        s_t = sVal[J];
        s_ti = sIdx[J];
    }

    const bool pen = (row & 7) == 7;
    if (pen) {
        __syncthreads();
        for (int w = tid; w < MASK_WORDS_PER_B; w += SEL_T) presRow[w] = 0u;
        __syncthreads();
        const int* bp = ids + (row >> 3) * L_;
        for (int k = tid; k < L_; k += SEL_T) {
            int t = bp[k];
            atomicOr(&presRow[t >> 5], 1u << (t & 31));
        }
    }
    __syncthreads();

    // ---- full-row background write (4x issue width vs r15) ----
    float* orow = out + (size_t)row * V;
    const unsigned mis = (unsigned)(((size_t)row * (size_t)V) & 3u);
    const int a0 = (int)((4u - mis) & 3u);          // scalar head elems
    const int nv = (V - a0) >> 2;                   // aligned f4 stores
    const int tailStart = a0 + (nv << 2);
    if (tid < a0) {
        int t = tid;
        orow[t] = (pen && ((presRow[t >> 5] >> (t & 31)) & 1u)) ? PEN_NEG : NEG_INF;
    }
    if (tid < V - tailStart) {
        int t = tailStart + tid;
        orow[t] = (pen && ((presRow[t >> 5] >> (t & 31)) & 1u)) ? PEN_NEG : NEG_INF;
    }
    float4* ob = reinterpret_cast<float4*>(orow + a0);
    if (!pen) {
        const float4 bg = make_float4(NEG_INF, NEG_INF, NEG_INF, NEG_INF);
        for (int j = tid; j < nv; j += SEL_T) ob[j] = bg;
    } else {
        for (int j = tid; j < nv; j += SEL_T) {
            int t = a0 + (j << 2);
            float4 bg;
            bg.x = ((presRow[t >> 5]     >> (t & 31))     & 1u) ? PEN_NEG : NEG_INF;
            bg.y = ((presRow[(t+1) >> 5] >> ((t+1) & 31)) & 1u) ? PEN_NEG : NEG_INF;
            bg.z = ((presRow[(t+2) >> 5] >> ((t+2) & 31)) & 1u) ? PEN_NEG : NEG_INF;
            bg.w = ((presRow[(t+3) >> 5] >> ((t+3) & 31)) & 1u) ? PEN_NEG : NEG_INF;
            ob[j] = bg;
        }
    }
    __syncthreads();   // drains vmcnt -> background ordered before kept stores

    // ---- overwrite kept tokens (kept set subset of candidates) ----
    float t = s_t;
    int tie = s_ti;
    if (tid < cnt) {
        float x = cX[tid];
        int tok = cI[tid];
        bool keep = (x > t) || (x == t && tok <= tie);
        if (keep) {
            float oo = x;   // exact v/0.8f, matches reference bits
            if (pen && ((presRow[tok >> 5] >> (tok & 31)) & 1u))
                oo = (oo < 0.0f) ? oo * 1.2f : oo * (1.0f / 1.2f);
            orow[tok] = oo;
        }
    }
}

// ---------------- safety fallback (ws too small; proven 3-kernel path) ----------------
#define CAND_CAP 4096
#define RT_THREADS 1024

__global__ __launch_bounds__(256) void mask_only_kernel(const int* __restrict__ ids,
                                                        unsigned* __restrict__ mask) {
    const int tid = threadIdx.x;
    const int b = blockIdx.x;
    __shared__ unsigned lds[MASK_WORDS_PER_B];
    for (int w = tid; w < MASK_WORDS_PER_B; w += 256) lds[w] = 0u;
    __syncthreads();
    const int* bp = ids + b * L_;
#pragma unroll
    for (int k = 0; k < L_ / 256; ++k) {
        int t = bp[k * 256 + tid];
        atomicOr(&lds[t >> 5], 1u << (t & 31));
    }
    __syncthreads();
    unsigned* mp = mask + b * MASK_WORDS_PER_B;
    for (int w = tid; w < MASK_WORDS_PER_B; w += 256) mp[w] = lds[w];
}

__device__ __forceinline__ int blockReduceSumRT(int v, int tid, int* s16) {
#pragma unroll
    for (int off = 32; off; off >>= 1) v += __shfl_down(v, off);
    __syncthreads();
    if ((tid & 63) == 0) s16[tid >> 6] = v;
    __syncthreads();
    int t = 0;
#pragma unroll
    for (int k = 0; k < RT_THREADS / 64; ++k) t += s16[k];
    return t;
}

__global__ __launch_bounds__(RT_THREADS, 8) void row_thresh_kernel(
        const float* __restrict__ logits, uint4* __restrict__ rowParam) {
    const int tid = threadIdx.x;
    const int row = blockIdx.x;
    if (row >= ROWS) return;
    const float* rp = logits + (size_t)row * V;

    __shared__ float candV[CAND_CAP];
    __shared__ int   candI[CAND_CAP];
    __shared__ float sVal[TOP_CAP];
    __shared__ int   sIdx[TOP_CAP];
    __shared__ double sExp[TOP_CAP];
    __shared__ int s_cnt, s_M;
    __shared__ int s_red[RT_THREADS / 64];

    const unsigned mis = (unsigned)(((size_t)row * (size_t)V) & 3u);
    const int a0 = (int)((4u - mis) & 3u);
    const int nv = (V - a0) >> 2;
    const int tailStart = a0 + (nv << 2);
    const float4* vp = reinterpret_cast<const float4*>(rp + a0);

    float TR = 2.4f;
    int cnt = 0;
    for (int attempt = 0; attempt < 12; ++attempt) {
        if (tid == 0) s_cnt = 0;
        __syncthreads();
        for (int base = tid; base < nv; base += 4 * RT_THREADS) {
            int i1 = base + RT_THREADS, i2 = base + 2 * RT_THREADS, i3 = base + 3 * RT_THREADS;
            float4 a = vp[base];
            float4 b = vp[i1 < nv ? i1 : nv - 1];
            float4 c = vp[i2 < nv ? i2 : nv - 1];
            float4 d = vp[i3 < nv ? i3 : nv - 1];
            float va[16] = {a.x, a.y, a.z, a.w, b.x, b.y, b.z, b.w,
                            c.x, c.y, c.z, c.w, d.x, d.y, d.z, d.w};
            int ib[4] = {base, i1, i2, i3};
            bool ok[4] = {true, i1 < nv, i2 < nv, i3 < nv};
#pragma unroll
            for (int q = 0; q < 4; ++q) {
                if (!ok[q]) continue;
#pragma unroll
                for (int cc = 0; cc < 4; ++cc) {
                    float v = va[q * 4 + cc];
                    if (v >= TR) {
                        int p = atomicAdd(&s_cnt, 1);
                        if (p < CAND_CAP) { candV[p] = v / 0.8f; candI[p] = a0 + (ib[q] << 2) + cc; }
                    }
                }
            }
        }
        if (tid < a0) {
            float v = rp[tid];
            if (v >= TR) {
                int p = atomicAdd(&s_cnt, 1);
                if (p < CAND_CAP) { candV[p] = v / 0.8f; candI[p] = tid; }
            }
        }
        if (tid < V - tailStart) {
            float v = rp[tailStart + tid];
            if (v >= TR) {
                int p = atomicAdd(&s_cnt, 1);
                if (p < CAND_CAP) { candV[p] = v / 0.8f; candI[p] = tailStart + tid; }
            }
        }
        __syncthreads();
        cnt = s_cnt;
        if (cnt >= 50 && cnt <= CAND_CAP) break;
        if (cnt < 50) TR -= 1.2f; else TR += 1.2f;
        __syncthreads();
    }
    if (cnt > CAND_CAP) cnt = CAND_CAP;

    if (tid < TOP_CAP) { sVal[tid] = -3.4e38f; sIdx[tid] = 0x7FFFFFFF; }
    __syncthreads();

    {
        float v0 = (tid < cnt) ? candV[tid] : -3.4e38f;
        int i0 = (tid < cnt) ? candI[tid] : 0x7FFFFFFF;
        float v1 = (tid + RT_THREADS < cnt) ? candV[tid + RT_THREADS] : -3.4e38f;
        int i1 = (tid + RT_THREADS < cnt) ? candI[tid + RT_THREADS] : 0x7FFFFFFF;
        float v2 = (tid + 2 * RT_THREADS < cnt) ? candV[tid + 2 * RT_THREADS] : -3.4e38f;
        int i2 = (tid + 2 * RT_THREADS < cnt) ? candI[tid + 2 * RT_THREADS] : 0x7FFFFFFF;
        float v3 = (tid + 3 * RT_THREADS < cnt) ? candV[tid + 3 * RT_THREADS] : -3.4e38f;
        int i3 = (tid + 3 * RT_THREADS < cnt) ? candI[tid + 3 * RT_THREADS] : 0x7FFFFFFF;
        int r0 = 0, r1 = 0, r2 = 0, r3 = 0;
        for (int j = 0; j < cnt; ++j) {
            float w = candV[j];
            int wi = candI[j];
            r0 += (w > v0) || (w == v0 && wi < i0);
            r1 += (w > v1) || (w == v1 && wi < i1);
            r2 += (w > v2) || (w == v2 && wi < i2);
            r3 += (w > v3) || (w == v3 && wi < i3);
        }
        if (tid < cnt && r0 < TOP_CAP) { sVal[r0] = v0; sIdx[r0] = i0; }
        if (tid + RT_THREADS < cnt && r1 < TOP_CAP) { sVal[r1] = v1; sIdx[r1] = i1; }
        if (tid + 2 * RT_THREADS < cnt && r2 < TOP_CAP) { sVal[r2] = v2; sIdx[r2] = i2; }
        if (tid + 3 * RT_THREADS < cnt && r3 < TOP_CAP) { sVal[r3] = v3; sIdx[r3] = i3; }
    }
    __syncthreads();

    if (tid == 0) {
        float kth = sVal[49];
        int M = 50;
        while (M < TOP_CAP && sVal[M] == kth) ++M;
        s_M = M;
    }
    __syncthreads();
    int M = s_M;
    if (tid < M) sExp[tid] = exp((double)sVal[tid] - (double)sVal[0]);
    __syncthreads();

    if (tid == 0) {
        double denom = 0.0;
#pragma unroll 1
        for (int i = 0; i < M; ++i) denom += sExp[i];
        double cum = 0.0;
        int J = M - 1;
#pragma unroll 1
        for (int i = 0; i < M; ++i) {
            cum += sExp[i] / denom;
            if (cum > 0.9) { J = i; break; }
        }
        float t = sVal[J];
        float w = t * 0.8f;
        unsigned wb = __float_as_uint(w);
        unsigned lo = 0xFFFFFFFFu, hi = 0u;
        for (int d = -4; d <= 4; ++d) {
            unsigned ub = wb + (unsigned)d;
            if (__uint_as_float(ub) / 0.8f == t) { if (ub < lo) lo = ub; if (ub > hi) hi = ub; }
        }
        rowParam[row] = make_uint4(lo, hi, (unsigned)sIdx[J], 0u);
    }
}

__global__ __launch_bounds__(256) void apply_kernel(const float4* __restrict__ in4,
                                                    const uint4* __restrict__ rowParam,
                                                    const unsigned* __restrict__ mask,
                                                    float4* __restrict__ out4) {
    int gid = blockIdx.x * 256 + threadIdx.x;
    int i0 = gid << 1;
    if (i0 >= NVEC) return;
    float4 a = in4[i0];
    float4 b = in4[i0 + 1];
    unsigned e = (unsigned)i0 << 2;
    unsigned row = e / (unsigned)V;
    unsigned tok0 = e - row * (unsigned)V;
    uint4 p0 = rowParam[row];
    bool crosses = (tok0 + 7u >= (unsigned)V);
    uint4 p1 = crosses ? rowParam[row + 1] : p0;
    float xs[8] = {a.x, a.y, a.z, a.w, b.x, b.y, b.z, b.w};
    float o[8];
#pragma unroll
    for (int c = 0; c < 8; ++c) {
        unsigned tok = tok0 + (unsigned)c;
        unsigned r = row;
        uint4 pp = p0;
        if (tok >= (unsigned)V) { tok -= (unsigned)V; r = row + 1u; pp = p1; }
        float v = xs[c];
        float vlo = __uint_as_float(pp.x);
        float vhi = __uint_as_float(pp.y);
        bool keep = (v > vhi) || (v >= vlo && tok <= pp.z);
        float oo = keep ? v * 1.25f : NEG_INF;
        if ((r & 7u) == 7u) {
            unsigned w = mask[(r >> 3) * MASK_WORDS_PER_B + (tok >> 5)];
            if ((w >> (tok & 31u)) & 1u) oo = (oo < 0.0f) ? oo * 1.2f : oo * (1.0f / 1.2f);
        }
        o[c] = oo;
    }
    out4[i0] = make_float4(o[0], o[1], o[2], o[3]);
    out4[i0 + 1] = make_float4(o[4], o[5], o[6], o[7]);
}

extern "C" void kernel_launch(void* const* d_in, const int* in_sizes, int n_in,
                              void* d_out, int out_size, void* d_ws, size_t ws_size,
                              hipStream_t stream) {
    const float* logits = (const float*)d_in[0];
    const int* ids = (const int*)d_in[1];
    float* out = (float*)d_out;

    if (ws_size >= WS_NEED) {
        unsigned* wcnt = (unsigned*)((char*)d_ws + WS_WCNT);
        uint2* gcand = (uint2*)((char*)d_ws + WS_GCAND);
        // r15 structure: gather (read-only) -> select (threshold + full-row
        // write + scatter), select widened to 1024 threads (32 waves/CU).
        gather_kernel<<<GW_BLOCKS, 256, 0, stream>>>((const float4*)logits, gcand, wcnt);
        select_kernel<<<ROWS, SEL_T, 0, stream>>>(logits, ids, gcand, wcnt, out);
    } else {
        uint4* rowParam = (uint4*)((char*)d_ws + WS_ROWPARAM);
        unsigned* mask = (unsigned*)((char*)d_ws + WS_MASK);
        mask_only_kernel<<<B_, 256, 0, stream>>>(ids, mask);
        row_thresh_kernel<<<ROWS, RT_THREADS, 0, stream>>>(logits, rowParam);
        apply_kernel<<<(NVEC / 2 + 255) / 256, 256, 0, stream>>>((const float4*)logits, rowParam,
                                                                 mask, (float4*)out);
    }
}

// Round 21
// 53.967 us; speedup vs baseline: 1.0859x; 1.0551x over previous
//
#include <hip/hip_runtime.h>
#include <stdint.h>

#define V 50257
#define B_ 64
#define S_ 8
#define ROWS (B_ * S_)
#define L_ 2048
#define NEG_INF -1000000000.0f
#define PEN_NEG (-1200000000.0f)   // NEG_INF * 1.2f, exact in fp32
#define MASK_WORDS_PER_B 1571      // ceil(50257/32)
#define TOTAL (ROWS * V)           // 25,731,584
#define NVEC (TOTAL / 4)           // 6,432,896 (exact)
#define TOP_CAP 64                 // top-k=50 plus headroom for exact ties at kth
#define TRAW 2.8f                  // raw cutoff; E[cnt]=128/row
#define F4L 7                      // float4s per lane
#define WCHUNK_F4 (64 * F4L)       // 448 f4 per wave chunk
#define ELEMS_PER_WAVE (WCHUNK_F4 * 4)   // 1792 (spans <= 2 rows)
#define NWAVES ((NVEC + WCHUNK_F4 - 1) / WCHUNK_F4)   // 14360
#define GW_BLOCKS ((NWAVES + 3) / 4)                  // 3590
#define WCAP 32                    // per-wave region (mean 9.1, sd 3)
#define CAPROW 512                 // per-row candidate cap in select

// ---- workspace layout ----
#define WS_WCNT    0                                   // 14360 u32 -> pad 65536
#define WS_GCAND   65536                               // 14360*32*8 = 3,676,160
#define WS_NEED    (WS_GCAND + (size_t)NWAVES * WCAP * 8)   // ~3.74 MB
// fallback layout (disjoint use; only when ws too small for fast path)
#define WS_ROWPARAM 0                                   // 512 * 16 B
#define WS_MASK     8192                                // 402176 B

__device__ __forceinline__ unsigned fkey(float f) {
    unsigned u = __float_as_uint(f);
    return (u & 0x80000000u) ? ~u : (u | 0x80000000u);
}

__device__ __forceinline__ int blockReduceSum256(int v, int tid, int* s4) {
#pragma unroll
    for (int off = 32; off; off >>= 1) v += __shfl_down(v, off);
    __syncthreads();
    if ((tid & 63) == 0) s4[tid >> 6] = v;
    __syncthreads();
    return s4[0] + s4[1] + s4[2] + s4[3];
}

// ---------------- gather: per-wave, no LDS / barriers / atomics ----------------

// Each wave owns f4 chunk [wid*448, +448). 7 asm loads, each followed by
// sched_barrier(0) so NOTHING (not even consumes) can interleave between the
// issues -> 7 truly outstanding loads/wave. One vmcnt(0)+sched_barrier, then
// consume into a depth-8 named-register shift queue. Wave-level prefix sum
// (shfl_up) assigns slots in the wave's PRIVATE gcand region; plain stores;
// lane 0 stores the count. Overflow (P~1e-12) flags select's exact fallback.
__global__ __launch_bounds__(256) void gather_kernel(const float4* __restrict__ in4,
                                                     uint2* __restrict__ gcand,
                                                     unsigned* __restrict__ wcnt) {
    const int wid = blockIdx.x * 4 + (threadIdx.x >> 6);
    if (wid >= NWAVES) return;
    const int lane = threadIdx.x & 63;
    const int b = wid * WCHUNK_F4 + lane;

    const float4* p0 = in4 + min(b,          NVEC - 1);
    const float4* p1 = in4 + min(b + 64,     NVEC - 1);
    const float4* p2 = in4 + min(b + 2 * 64, NVEC - 1);
    const float4* p3 = in4 + min(b + 3 * 64, NVEC - 1);
    const float4* p4 = in4 + min(b + 4 * 64, NVEC - 1);
    const float4* p5 = in4 + min(b + 5 * 64, NVEC - 1);
    const float4* p6 = in4 + min(b + 6 * 64, NVEC - 1);

    float4 va0, va1, va2, va3, va4, va5, va6;
#define LOADPIN(dst, src)                                                     \
    asm volatile("global_load_dwordx4 %0, %1, off" : "=v"(dst) : "v"(src));   \
    __builtin_amdgcn_sched_barrier(0);
    LOADPIN(va0, p0) LOADPIN(va1, p1) LOADPIN(va2, p2) LOADPIN(va3, p3)
    LOADPIN(va4, p4) LOADPIN(va5, p5) LOADPIN(va6, p6)
#undef LOADPIN
    asm volatile("s_waitcnt vmcnt(0)" ::: "memory");
    __builtin_amdgcn_sched_barrier(0);

    float q0v = 0.f, q1v = 0.f, q2v = 0.f, q3v = 0.f, q4v = 0.f, q5v = 0.f, q6v = 0.f, q7v = 0.f;
    int q0i = 0, q1i = 0, q2i = 0, q3i = 0, q4i = 0, q5i = 0, q6i = 0, q7i = 0;
    int nh = 0;

#define INS(val, ei)                                                          \
    if ((val) >= TRAW) {                                                      \
        q7v = q6v; q7i = q6i; q6v = q5v; q6i = q5i; q5v = q4v; q5i = q4i;     \
        q4v = q3v; q4i = q3i; q3v = q2v; q3i = q2i; q2v = q1v; q2i = q1i;     \
        q1v = q0v; q1i = q0i; q0v = (val); q0i = (ei); ++nh;                  \
    }
#define CONSUME(vv, kk)                                                       \
    {                                                                         \
        int i = b + (kk) * 64;                                                \
        if (i < NVEC) {                                                       \
            int e = i << 2;                                                   \
            INS((vv).x, e)                                                    \
            INS((vv).y, e + 1)                                                \
            INS((vv).z, e + 2)                                                \
            INS((vv).w, e + 3)                                                \
        }                                                                     \
    }
    CONSUME(va0, 0) CONSUME(va1, 1) CONSUME(va2, 2) CONSUME(va3, 3)
    CONSUME(va4, 4) CONSUME(va5, 5) CONSUME(va6, 6)
#undef CONSUME
#undef INS

    // wave prefix-sum of per-lane counts -> private slots; plain stores only
    int m = nh > 8 ? 8 : nh;
    int incl = m;
#pragma unroll
    for (int d = 1; d < 64; d <<= 1) {
        int t = __shfl_up(incl, d);
        if (lane >= d) incl += t;
    }
    int excl = incl - m;
    int total = __shfl(incl, 63);
    bool of = (total > WCAP) || __any(nh > 8);

    size_t rb = (size_t)wid * WCAP;
    if (m >= 1 && excl + 0 < WCAP) gcand[rb + excl + 0] = make_uint2((unsigned)q0i, __float_as_uint(q0v));
    if (m >= 2 && excl + 1 < WCAP) gcand[rb + excl + 1] = make_uint2((unsigned)q1i, __float_as_uint(q1v));
    if (m >= 3 && excl + 2 < WCAP) gcand[rb + excl + 2] = make_uint2((unsigned)q2i, __float_as_uint(q2v));
    if (m >= 4 && excl + 3 < WCAP) gcand[rb + excl + 3] = make_uint2((unsigned)q3i, __float_as_uint(q3v));
    if (m >= 5 && excl + 4 < WCAP) gcand[rb + excl + 4] = make_uint2((unsigned)q4i, __float_as_uint(q4v));
    if (m >= 6 && excl + 5 < WCAP) gcand[rb + excl + 5] = make_uint2((unsigned)q5i, __float_as_uint(q5v));
    if (m >= 7 && excl + 6 < WCAP) gcand[rb + excl + 6] = make_uint2((unsigned)q6i, __float_as_uint(q6v));
    if (m >= 8 && excl + 7 < WCAP) gcand[rb + excl + 7] = make_uint2((unsigned)q7i, __float_as_uint(q7v));
    if (lane == 0) wcnt[wid] = of ? 1000000u : (unsigned)total;
}

// ---------------- select: exact threshold + FULL-ROW write (validated) ----------------

__global__ __launch_bounds__(256) void select_kernel(const float* __restrict__ logits,
                                                     const int* __restrict__ ids,
                                                     const uint2* __restrict__ gcand,
                                                     const unsigned* __restrict__ wcnt,
                                                     float* __restrict__ out) {
    const int row = blockIdx.x;
    const int tid = threadIdx.x;
    __shared__ float cX[CAPROW];
    __shared__ unsigned cR[CAPROW];
    __shared__ int cI[CAPROW];
    __shared__ float sVal[TOP_CAP];
    __shared__ int sIdx[TOP_CAP];
    __shared__ double sExp[TOP_CAP];
    __shared__ unsigned presRow[MASK_WORDS_PER_B];
    __shared__ unsigned s_wc[40];
    __shared__ int s_c, s_M, s_bad, s_ti;
    __shared__ float s_t;
    __shared__ int s_red[4];

    const float* rp = logits + (size_t)row * V;
    const unsigned e0 = (unsigned)row * (unsigned)V;
    if (tid == 0) { s_c = 0; s_bad = 0; }
    __syncthreads();

    {   // flat parallel scan of the ~29 wave-regions overlapping this row
        const int r0 = (int)(e0 / (unsigned)ELEMS_PER_WAVE);
        const int r1 = (int)((e0 + V - 1) / (unsigned)ELEMS_PER_WAVE);
        const int nr = r1 - r0 + 1;                 // <= 30
        if (tid < nr) s_wc[tid] = wcnt[r0 + tid];
        __syncthreads();
        const int nslots = nr * WCAP;
        for (int j = tid; j < nslots; j += 256) {
            int r = j >> 5;                          // WCAP = 32
            int sl = j & 31;
            unsigned c = s_wc[r];
            if (c > (unsigned)WCAP) { s_bad = 1; c = WCAP; }   // benign race
            if (sl < (int)c) {
                uint2 u = gcand[(size_t)(r0 + r) * WCAP + sl];
                if (u.x / (unsigned)V == (unsigned)row) {
                    int p = atomicAdd(&s_c, 1);
                    if (p < CAPROW) {
                        cR[p] = u.y;
                        cX[p] = __uint_as_float(u.y) / 0.8f;
                        cI[p] = (int)(u.x - e0);
                    }
                }
            }
        }
    }
    __syncthreads();
    int cnt = s_c;
    if (s_bad || cnt < 50 || cnt > CAPROW) {
        // Pathological-only exact fallback: bisect raw key space for the 50th
        // largest, re-gather with 2-ulp slack.
        unsigned lo = 0u, hi = 0xFFFFFFFFu;
        while (lo < hi) {
            unsigned mid = lo + ((hi - lo) >> 1) + 1u;
            int c = 0;
            for (int j = tid; j < V; j += 256) c += (int)(fkey(rp[j]) >= mid);
            c = blockReduceSum256(c, tid, s_red);
            if (c >= 50) lo = mid; else hi = mid - 1u;
        }
        unsigned gl = (lo > 2u) ? lo - 2u : 0u;
        __syncthreads();
        if (tid == 0) s_c = 0;
        __syncthreads();
        for (int j = tid; j < V; j += 256) {
            float v = rp[j];
            if (fkey(v) >= gl) {
                int p = atomicAdd(&s_c, 1);
                if (p < CAPROW) { cR[p] = __float_as_uint(v); cX[p] = v / 0.8f; cI[p] = j; }
            }
        }
        __syncthreads();
        cnt = min(s_c, CAPROW);
    }

    if (tid < TOP_CAP) { sVal[tid] = -3.4e38f; sIdx[tid] = 0x7FFFFFFF; }
    __syncthreads();

    // Rank-sort: (x desc, token idx asc); LDS broadcast reads conflict-free.
    {
        float v0 = -3.4e38f, v1 = -3.4e38f;
        int i0 = 0x7FFFFFFF, i1 = 0x7FFFFFFF;
        if (tid < cnt) { v0 = cX[tid]; i0 = cI[tid]; }
        if (tid + 256 < cnt) { v1 = cX[tid + 256]; i1 = cI[tid + 256]; }
        int r0 = 0, r1 = 0;
        for (int j = 0; j < cnt; ++j) {
            float w = cX[j];
            int wi = cI[j];
            r0 += (w > v0) || (w == v0 && wi < i0);
            r1 += (w > v1) || (w == v1 && wi < i1);
        }
        if (tid < cnt && r0 < TOP_CAP) { sVal[r0] = v0; sIdx[r0] = i0; }
        if (tid + 256 < cnt && r1 < TOP_CAP) { sVal[r1] = v1; sIdx[r1] = i1; }
    }
    __syncthreads();

    if (tid == 0) {
        float kth = sVal[49];
        int M = 50;
        while (M < TOP_CAP && sVal[M] == kth) ++M;   // include exact ties at kth
        s_M = M;
    }
    __syncthreads();
    int M = s_M;
    if (tid < M) sExp[tid] = exp((double)sVal[tid] - (double)sVal[0]);
    __syncthreads();
    if (tid == 0) {
        double denom = 0.0;
        for (int i = 0; i < M; ++i) denom += sExp[i];
        double cum = 0.0;
        int J = M - 1;
        for (int i = 0; i < M; ++i) {
            cum += sExp[i] / denom;
            if (cum > 0.9) { J = i; break; }
        }
        s_t = sVal[J];
        s_ti = sIdx[J];
    }

    const bool pen = (row & 7) == 7;
    if (pen) {
        __syncthreads();
        for (int w = tid; w < MASK_WORDS_PER_B; w += 256) presRow[w] = 0u;
        __syncthreads();
        const int* bp = ids + (row >> 3) * L_;
#pragma unroll
        for (int k = 0; k < L_ / 256; ++k) {
            int t = bp[k * 256 + tid];
            atomicOr(&presRow[t >> 5], 1u << (t & 31));
        }
    }
    __syncthreads();

    // full-row background write (alignment-corrected)
    float* orow = out + (size_t)row * V;
    const unsigned mis = (unsigned)(((size_t)row * (size_t)V) & 3u);
    const int a0 = (int)((4u - mis) & 3u);
    const int nv = (V - a0) >> 2;
    const int tailStart = a0 + (nv << 2);
    if (tid < a0) {
        int t = tid;
        orow[t] = (pen && ((presRow[t >> 5] >> (t & 31)) & 1u)) ? PEN_NEG : NEG_INF;
    }
    if (tid < V - tailStart) {
        int t = tailStart + tid;
        orow[t] = (pen && ((presRow[t >> 5] >> (t & 31)) & 1u)) ? PEN_NEG : NEG_INF;
    }
    float4* ob = reinterpret_cast<float4*>(orow + a0);
    if (!pen) {
        const float4 bg = make_float4(NEG_INF, NEG_INF, NEG_INF, NEG_INF);
        for (int j = tid; j < nv; j += 256) ob[j] = bg;
    } else {
        for (int j = tid; j < nv; j += 256) {
            int t = a0 + (j << 2);
            float4 bg;
            bg.x = ((presRow[t >> 5]     >> (t & 31))     & 1u) ? PEN_NEG : NEG_INF;
            bg.y = ((presRow[(t+1) >> 5] >> ((t+1) & 31)) & 1u) ? PEN_NEG : NEG_INF;
            bg.z = ((presRow[(t+2) >> 5] >> ((t+2) & 31)) & 1u) ? PEN_NEG : NEG_INF;
            bg.w = ((presRow[(t+3) >> 5] >> ((t+3) & 31)) & 1u) ? PEN_NEG : NEG_INF;
            ob[j] = bg;
        }
    }
    __syncthreads();   // drains vmcnt -> background ordered before kept stores

    float t = s_t;
    int tie = s_ti;
    for (int j = tid; j < cnt; j += 256) {
        float x = cX[j];
        int tok = cI[j];
        bool keep = (x > t) || (x == t && tok <= tie);
        if (keep) {
            float oo = x;   // exact v/0.8f, matches reference bits
            if (pen && ((presRow[tok >> 5] >> (tok & 31)) & 1u))
                oo = (oo < 0.0f) ? oo * 1.2f : oo * (1.0f / 1.2f);
            orow[tok] = oo;
        }
    }
}

// ---------------- safety fallback (ws too small; proven 3-kernel path) ----------------
#define CAND_CAP 4096
#define RT_THREADS 1024

__global__ __launch_bounds__(256) void mask_only_kernel(const int* __restrict__ ids,
                                                        unsigned* __restrict__ mask) {
    const int tid = threadIdx.x;
    const int b = blockIdx.x;
    __shared__ unsigned lds[MASK_WORDS_PER_B];
    for (int w = tid; w < MASK_WORDS_PER_B; w += 256) lds[w] = 0u;
    __syncthreads();
    const int* bp = ids + b * L_;
#pragma unroll
    for (int k = 0; k < L_ / 256; ++k) {
        int t = bp[k * 256 + tid];
        atomicOr(&lds[t >> 5], 1u << (t & 31));
    }
    __syncthreads();
    unsigned* mp = mask + b * MASK_WORDS_PER_B;
    for (int w = tid; w < MASK_WORDS_PER_B; w += 256) mp[w] = lds[w];
}

__global__ __launch_bounds__(RT_THREADS, 8) void row_thresh_kernel(
        const float* __restrict__ logits, uint4* __restrict__ rowParam) {
    const int tid = threadIdx.x;
    const int row = blockIdx.x;
    if (row >= ROWS) return;
    const float* rp = logits + (size_t)row * V;

    __shared__ float candV[CAND_CAP];
    __shared__ int   candI[CAND_CAP];
    __shared__ float sVal[TOP_CAP];
    __shared__ int   sIdx[TOP_CAP];
    __shared__ double sExp[TOP_CAP];
    __shared__ int s_cnt, s_M;
    __shared__ int s_red[RT_THREADS / 64];

    const unsigned mis = (unsigned)(((size_t)row * (size_t)V) & 3u);
    const int a0 = (int)((4u - mis) & 3u);
    const int nv = (V - a0) >> 2;
    const int tailStart = a0 + (nv << 2);
    const float4* vp = reinterpret_cast<const float4*>(rp + a0);

    float TR = 2.4f;
    int cnt = 0;
    for (int attempt = 0; attempt < 12; ++attempt) {
        if (tid == 0) s_cnt = 0;
        __syncthreads();
        for (int base = tid; base < nv; base += 4 * RT_THREADS) {
            int i1 = base + RT_THREADS, i2 = base + 2 * RT_THREADS, i3 = base + 3 * RT_THREADS;
            float4 a = vp[base];
            float4 b = vp[i1 < nv ? i1 : nv - 1];
            float4 c = vp[i2 < nv ? i2 : nv - 1];
            float4 d = vp[i3 < nv ? i3 : nv - 1];
            float va[16] = {a.x, a.y, a.z, a.w, b.x, b.y, b.z, b.w,
                            c.x, c.y, c.z, c.w, d.x, d.y, d.z, d.w};
            int ib[4] = {base, i1, i2, i3};
            bool ok[4] = {true, i1 < nv, i2 < nv, i3 < nv};
#pragma unroll
            for (int q = 0; q < 4; ++q) {
                if (!ok[q]) continue;
#pragma unroll
                for (int cc = 0; cc < 4; ++cc) {
                    float v = va[q * 4 + cc];
                    if (v >= TR) {
                        int p = atomicAdd(&s_cnt, 1);
                        if (p < CAND_CAP) { candV[p] = v / 0.8f; candI[p] = a0 + (ib[q] << 2) + cc; }
                    }
                }
            }
        }
        if (tid < a0) {
            float v = rp[tid];
            if (v >= TR) {
                int p = atomicAdd(&s_cnt, 1);
                if (p < CAND_CAP) { candV[p] = v / 0.8f; candI[p] = tid; }
            }
        }
        if (tid < V - tailStart) {
            float v = rp[tailStart + tid];
            if (v >= TR) {
                int p = atomicAdd(&s_cnt, 1);
                if (p < CAND_CAP) { candV[p] = v / 0.8f; candI[p] = tailStart + tid; }
            }
        }
        __syncthreads();
        cnt = s_cnt;
        if (cnt >= 50 && cnt <= CAND_CAP) break;
        if (cnt < 50) TR -= 1.2f; else TR += 1.2f;
        __syncthreads();
    }
    if (cnt > CAND_CAP) cnt = CAND_CAP;

    if (tid < TOP_CAP) { sVal[tid] = -3.4e38f; sIdx[tid] = 0x7FFFFFFF; }
    __syncthreads();

    {
        float v0 = (tid < cnt) ? candV[tid] : -3.4e38f;
        int i0 = (tid < cnt) ? candI[tid] : 0x7FFFFFFF;
        float v1 = (tid + RT_THREADS < cnt) ? candV[tid + RT_THREADS] : -3.4e38f;
        int i1 = (tid + RT_THREADS < cnt) ? candI[tid + RT_THREADS] : 0x7FFFFFFF;
        float v2 = (tid + 2 * RT_THREADS < cnt) ? candV[tid + 2 * RT_THREADS] : -3.4e38f;
        int i2 = (tid + 2 * RT_THREADS < cnt) ? candI[tid + 2 * RT_THREADS] : 0x7FFFFFFF;
        float v3 = (tid + 3 * RT_THREADS < cnt) ? candV[tid + 3 * RT_THREADS] : -3.4e38f;
        int i3 = (tid + 3 * RT_THREADS < cnt) ? candI[tid + 3 * RT_THREADS] : 0x7FFFFFFF;
        int r0 = 0, r1 = 0, r2 = 0, r3 = 0;
        for (int j = 0; j < cnt; ++j) {
            float w = candV[j];
            int wi = candI[j];
            r0 += (w > v0) || (w == v0 && wi < i0);
            r1 += (w > v1) || (w == v1 && wi < i1);
            r2 += (w > v2) || (w == v2 && wi < i2);
            r3 += (w > v3) || (w == v3 && wi < i3);
        }
        if (tid < cnt && r0 < TOP_CAP) { sVal[r0] = v0; sIdx[r0] = i0; }
        if (tid + RT_THREADS < cnt && r1 < TOP_CAP) { sVal[r1] = v1; sIdx[r1] = i1; }
        if (tid + 2 * RT_THREADS < cnt && r2 < TOP_CAP) { sVal[r2] = v2; sIdx[r2] = i2; }
        if (tid + 3 * RT_THREADS < cnt && r3 < TOP_CAP) { sVal[r3] = v3; sIdx[r3] = i3; }
    }
    __syncthreads();

    if (tid == 0) {
        float kth = sVal[49];
        int M = 50;
        while (M < TOP_CAP && sVal[M] == kth) ++M;
        s_M = M;
    }
    __syncthreads();
    int M = s_M;
    if (tid < M) sExp[tid] = exp((double)sVal[tid] - (double)sVal[0]);
    __syncthreads();

    if (tid == 0) {
        double denom = 0.0;
#pragma unroll 1
        for (int i = 0; i < M; ++i) denom += sExp[i];
        double cum = 0.0;
        int J = M - 1;
#pragma unroll 1
        for (int i = 0; i < M; ++i) {
            cum += sExp[i] / denom;
            if (cum > 0.9) { J = i; break; }
        }
        float t = sVal[J];
        float w = t * 0.8f;
        unsigned wb = __float_as_uint(w);
        unsigned lo = 0xFFFFFFFFu, hi = 0u;
        for (int d = -4; d <= 4; ++d) {
            unsigned ub = wb + (unsigned)d;
            if (__uint_as_float(ub) / 0.8f == t) { if (ub < lo) lo = ub; if (ub > hi) hi = ub; }
        }
        rowParam[row] = make_uint4(lo, hi, (unsigned)sIdx[J], 0u);
    }
}

__global__ __launch_bounds__(256) void apply_kernel(const float4* __restrict__ in4,
                                                    const uint4* __restrict__ rowParam,
                                                    const unsigned* __restrict__ mask,
                                                    float4* __restrict__ out4) {
    int gid = blockIdx.x * 256 + threadIdx.x;
    int i0 = gid << 1;
    if (i0 >= NVEC) return;
    float4 a = in4[i0];
    float4 b = in4[i0 + 1];
    unsigned e = (unsigned)i0 << 2;
    unsigned row = e / (unsigned)V;
    unsigned tok0 = e - row * (unsigned)V;
    uint4 p0 = rowParam[row];
    bool crosses = (tok0 + 7u >= (unsigned)V);
    uint4 p1 = crosses ? rowParam[row + 1] : p0;
    float xs[8] = {a.x, a.y, a.z, a.w, b.x, b.y, b.z, b.w};
    float o[8];
#pragma unroll
    for (int c = 0; c < 8; ++c) {
        unsigned tok = tok0 + (unsigned)c;
        unsigned r = row;
        uint4 pp = p0;
        if (tok >= (unsigned)V) { tok -= (unsigned)V; r = row + 1u; pp = p1; }
        float v = xs[c];
        float vlo = __uint_as_float(pp.x);
        float vhi = __uint_as_float(pp.y);
        bool keep = (v > vhi) || (v >= vlo && tok <= pp.z);
        float oo = keep ? v * 1.25f : NEG_INF;
        if ((r & 7u) == 7u) {
            unsigned w = mask[(r >> 3) * MASK_WORDS_PER_B + (tok >> 5)];
            if ((w >> (tok & 31u)) & 1u) oo = (oo < 0.0f) ? oo * 1.2f : oo * (1.0f / 1.2f);
        }
        o[c] = oo;
    }
    out4[i0] = make_float4(o[0], o[1], o[2], o[3]);
    out4[i0 + 1] = make_float4(o[4], o[5], o[6], o[7]);
}

extern "C" void kernel_launch(void* const* d_in, const int* in_sizes, int n_in,
                              void* d_out, int out_size, void* d_ws, size_t ws_size,
                              hipStream_t stream) {
    const float* logits = (const float*)d_in[0];
    const int* ids = (const int*)d_in[1];
    float* out = (float*)d_out;

    if (ws_size >= WS_NEED) {
        unsigned* wcnt = (unsigned*)((char*)d_ws + WS_WCNT);
        uint2* gcand = (uint2*)((char*)d_ws + WS_GCAND);
        // r15 best-known structure (54.0 us): gather (per-wave, no
        // LDS/barrier/atomic, 7-deep pinned loads) -> select (threshold +
        // full-row write + scatter)
        gather_kernel<<<GW_BLOCKS, 256, 0, stream>>>((const float4*)logits, gcand, wcnt);
        select_kernel<<<ROWS, 256, 0, stream>>>(logits, ids, gcand, wcnt, out);
    } else {
        uint4* rowParam = (uint4*)((char*)d_ws + WS_ROWPARAM);
        unsigned* mask = (unsigned*)((char*)d_ws + WS_MASK);
        mask_only_kernel<<<B_, 256, 0, stream>>>(ids, mask);
        row_thresh_kernel<<<ROWS, RT_THREADS, 0, stream>>>(logits, rowParam);
        apply_kernel<<<(NVEC / 2 + 255) / 256, 256, 0, stream>>>((const float4*)logits, rowParam,
                                                                 mask, (float4*)out);
    }
}